// Round 7
// baseline (361.810 us; speedup 1.0000x reference)
//
#include <hip/hip_runtime.h>
#include <hip/hip_bf16.h>
#include <cstdint>

#define NEG_SLOPE 0.2f
#define BUCKET_SHIFT 9    // 512 nodes per bucket
#define CHUNK 4096        // edges per bucketing block

typedef __attribute__((ext_vector_type(4))) int            i32x4;
typedef __attribute__((ext_vector_type(4))) float          f32x4;
typedef __attribute__((ext_vector_type(8))) unsigned short u16x8;
typedef __attribute__((ext_vector_type(4))) unsigned short u16x4;

__device__ inline unsigned short f2bf(float f) {  // round-to-nearest-even
    unsigned xi = __float_as_uint(f);
    unsigned r = xi + 0x7fffu + ((xi >> 16) & 1u);
    return (unsigned short)(r >> 16);
}
__device__ inline float bflo(unsigned g) { return __uint_as_float(g << 16); }
__device__ inline float bfhi(unsigned g) { return __uint_as_float(g & 0xffff0000u); }

__device__ inline int get_ei(const int* ei, int is64, long idx) {
    return is64 ? ei[2 * idx] : ei[(int)idx];
}

// In-block int64 detection: OR of odd words of the first 2048 src entries.
__device__ inline int detect_is64(const int* __restrict__ ei, int tid) {
    __shared__ int dred[4];
    int v = 0;
    for (int i = tid; i < 2048; i += 256) v |= ei[2 * i + 1];
#pragma unroll
    for (int off = 32; off; off >>= 1) v |= __shfl_xor(v, off);
    if ((tid & 63) == 0) dred[tid >> 6] = v;
    __syncthreads();
    int r = dred[0] | dred[1] | dred[2] | dred[3];
    __syncthreads();
    return (r == 0) ? 1 : 0;
}

// ---------------------------------------------------------------------------
// p1 body: per-chunk LDS histogram -> global atomicAdd into bucket totals BT.
// (The per-chunk scan is gone: p3 reserves ranges atomically instead.)
// ---------------------------------------------------------------------------
__device__ void p1_body(const int* __restrict__ ei, int* __restrict__ BT,
                        int E, int n, int bid) {
    __shared__ int cnt[256];
    int tid = threadIdx.x;
    int is64 = detect_is64(ei, tid);
    int nbuk = (n + 511) >> BUCKET_SHIFT;
    for (int b = tid; b < nbuk; b += 256) cnt[b] = 0;
    __syncthreads();
    int total = E + n;
    int beg = bid * CHUNK;
    int end = beg + CHUNK; if (end > total) end = total;
    for (int i = beg + tid; i < end; i += 256) {
        int d = (i < E) ? get_ei(ei, is64, (long)E + i) : (i - E);
        atomicAdd(&cnt[d >> BUCKET_SHIFT], 1);
    }
    __syncthreads();
    for (int b = tid; b < nbuk; b += 256)
        if (cnt[b]) atomicAdd(&BT[b], cnt[b]);
}

// ---------------------------------------------------------------------------
// MFMA projection body (shared by fused D1 and standalone proj2).
// ---------------------------------------------------------------------------
#define MFMA_BF16(acc, a, b) \
    asm("s_nop 1\n\tv_mfma_f32_16x16x32_bf16 %0, %1, %2, %0" \
        : "+v"(acc) : "v"(a), "v"(b))

template <int KT, bool XBF>   // K = 32*KT
__device__ void proj_body(const void* __restrict__ xin,
                          const unsigned short* __restrict__ Wp,
                          const float* __restrict__ att_s,
                          const float* __restrict__ att_d,
                          unsigned short* __restrict__ h2,
                          float* __restrict__ asrc,
                          float* __restrict__ adst, int n, int bid) {
    constexpr int K = 32 * KT;
    __shared__ alignas(16) unsigned short lb[4][16 * 72];
    int tid = threadIdx.x;
    int wid = tid >> 6, l = tid & 63;
    int lm = l & 15, lg = l >> 4;

    int node0 = bid * 64 + wid * 16;
    if (node0 >= n) return;   // wave-uniform; no block barriers used

    float as_c[4], ad_c[4];
#pragma unroll
    for (int ct = 0; ct < 4; ++ct) {
        as_c[ct] = att_s[16 * ct + lm];
        ad_c[ct] = att_d[16 * ct + lm];
    }

    f32x4 acc[4] = {};
    int arow = node0 + lm;
    bool rowok = arow < n;

#pragma unroll
    for (int kt = 0; kt < KT; ++kt) {
        i32x4 af = {0, 0, 0, 0};
        if (XBF) {
            const unsigned short* xb = (const unsigned short*)xin
                                       + (size_t)arow * K + 32 * kt + 8 * lg;
            if (rowok) af = *(const i32x4*)xb;
        } else {
            const float* xp = (const float*)xin + (size_t)arow * K + 8 * lg + 32 * kt;
            float4 v0 = make_float4(0.f, 0.f, 0.f, 0.f);
            float4 v1 = v0;
            if (rowok) {
                v0 = *(const float4*)(xp);
                v1 = *(const float4*)(xp + 4);
            }
            af[0] = (int)((unsigned)f2bf(v0.x) | ((unsigned)f2bf(v0.y) << 16));
            af[1] = (int)((unsigned)f2bf(v0.z) | ((unsigned)f2bf(v0.w) << 16));
            af[2] = (int)((unsigned)f2bf(v1.x) | ((unsigned)f2bf(v1.y) << 16));
            af[3] = (int)((unsigned)f2bf(v1.z) | ((unsigned)f2bf(v1.w) << 16));
        }
#pragma unroll
        for (int ct = 0; ct < 4; ++ct) {
            i32x4 bf = *(const i32x4*)(Wp + (((kt * 4 + ct) * 64) + l) * 8);
            MFMA_BF16(acc[ct], af, bf);
        }
    }
    asm volatile("s_nop 7\n\ts_nop 7"
                 : "+v"(acc[0]), "+v"(acc[1]), "+v"(acc[2]), "+v"(acc[3]));

    float ps[4], pd[4];
#pragma unroll
    for (int r = 0; r < 4; ++r) {
        float s = 0.f, d = 0.f;
#pragma unroll
        for (int ct = 0; ct < 4; ++ct) {
            s = fmaf(acc[ct][r], as_c[ct], s);
            d = fmaf(acc[ct][r], ad_c[ct], d);
        }
        ps[r] = s; pd[r] = d;
    }
#pragma unroll
    for (int off = 1; off < 16; off <<= 1) {
#pragma unroll
        for (int r = 0; r < 4; ++r) {
            ps[r] += __shfl_xor(ps[r], off);
            pd[r] += __shfl_xor(pd[r], off);
        }
    }
    if (lm == 0) {
#pragma unroll
        for (int r = 0; r < 4; ++r) {
            int node = node0 + 4 * lg + r;
            if (node < n) { asrc[node] = ps[r]; adst[node] = pd[r]; }
        }
    }

    unsigned short* wb = lb[wid];
#pragma unroll
    for (int ct = 0; ct < 4; ++ct)
#pragma unroll
        for (int r = 0; r < 4; ++r)
            wb[(4 * lg + r) * 72 + 16 * ct + lm] = f2bf(acc[ct][r]);
    asm volatile("s_waitcnt lgkmcnt(0)" ::: "memory");
    int ch = l & 7;
#pragma unroll
    for (int p = 0; p < 2; ++p) {
        int rr = (l >> 3) + 8 * p;
        u16x8 ov = *(const u16x8*)(wb + rr * 72 + 8 * ch);
        int onode = node0 + rr;
        if (onode < n)
            *(u16x8*)(h2 + (size_t)onode * 64 + 8 * ch) = ov;
    }
}

// ---------------------------------------------------------------------------
// D0: pack W fragments (blocks 0..5) + zero bucket totals (block 6).
// ---------------------------------------------------------------------------
__global__ __launch_bounds__(256) void prep_kernel(const float* __restrict__ W1,
                                                   const float* __restrict__ W2,
                                                   unsigned short* __restrict__ wp1,
                                                   unsigned short* __restrict__ wp2,
                                                   int* __restrict__ BT, int nbuk) {
    if (blockIdx.x == 6) {
        for (int b = threadIdx.x; b < nbuk; b += 256) BT[b] = 0;
        return;
    }
    int t = blockIdx.x * 256 + threadIdx.x;   // < 1536 = 24 frags * 64 lanes
    int f = t >> 6, l = t & 63;
    int lm = l & 15, lg = l >> 4;
    const float* W = (f < 16) ? W1 : W2;
    unsigned short* wp = (f < 16) ? wp1 : wp2;
    int idx = (f < 16) ? f : (f - 16);
    int kt = idx >> 2, ct = idx & 3;
    union { u16x8 v; unsigned short u[8]; } o;
#pragma unroll
    for (int e = 0; e < 8; ++e)
        o.u[e] = f2bf(W[(size_t)(32 * kt + 8 * lg + e) * 64 + 16 * ct + lm]);
    *(u16x8*)(wp + ((size_t)idx * 64 + l) * 8) = o.v;
}

// ---------------------------------------------------------------------------
// D1: fused proj1 (blocks [0,pgrid)) || p1 histogram (blocks [pgrid, ...)).
// Fully independent work -- proj1's latency hides the whole p1 pass.
// ---------------------------------------------------------------------------
__global__ __launch_bounds__(256) void fused1(const float* __restrict__ x,
                                              const unsigned short* __restrict__ wp1,
                                              const float* __restrict__ as1,
                                              const float* __restrict__ ad1,
                                              unsigned short* __restrict__ h2,
                                              float* __restrict__ asrc,
                                              float* __restrict__ adst, int n,
                                              const int* __restrict__ ei,
                                              int* __restrict__ BT, int E, int pgrid) {
    if ((int)blockIdx.x < pgrid)
        proj_body<4, false>(x, wp1, as1, ad1, h2, asrc, adst, n, blockIdx.x);
    else
        p1_body(ei, BT, E, n, blockIdx.x - pgrid);
}

// ---------------------------------------------------------------------------
// D2: one block -- exclusive scan of bucket totals -> BB (+sentinel), cur=BB.
// ---------------------------------------------------------------------------
__global__ __launch_bounds__(256) void scan_bt(const int* __restrict__ BT,
                                               int* __restrict__ BB,
                                               int* __restrict__ cur, int nbuk) {
    __shared__ int s[256];
    int t = threadIdx.x;
    int v = (t < nbuk) ? BT[t] : 0;
    s[t] = v;
    __syncthreads();
    for (int off = 1; off < 256; off <<= 1) {
        int u = (t >= off) ? s[t - off] : 0;
        __syncthreads();
        s[t] += u;
        __syncthreads();
    }
    int exc = s[t] - v;
    if (t < nbuk) { BB[t] = exc; cur[t] = exc; }
    if (t == 0) BB[nbuk] = s[255];    // total == T
}

// ---------------------------------------------------------------------------
// D3: scatter with atomic range reservation. Stash chunk in LDS (value +
// bucket id), count per bucket, reserve [base, base+cnt) via one global
// atomicAdd per (block,bucket), then scatter from LDS. Within-bucket order
// is arbitrary -- p4 re-sorts by node and aggregation is order-free.
// ---------------------------------------------------------------------------
__global__ __launch_bounds__(256) void p3_scatter(const int* __restrict__ ei,
                                                  int* __restrict__ cur,
                                                  int* __restrict__ sorted,
                                                  int E, int n) {
    __shared__ int stash[CHUNK];            // 16 KB
    __shared__ unsigned char stashB[CHUNK]; // 4 KB bucket ids (nbuk <= 256)
    __shared__ int cnt[256];
    __shared__ int base[256];
    int tid = threadIdx.x;
    int is64 = detect_is64(ei, tid);
    int nbuk = (n + 511) >> BUCKET_SHIFT;
    for (int b = tid; b < nbuk; b += 256) cnt[b] = 0;
    __syncthreads();
    int total = E + n;
    int beg = blockIdx.x * CHUNK;
    int end = beg + CHUNK; if (end > total) end = total;
    for (int i = beg + tid; i < end; i += 256) {
        int s, d;
        if (i < E) {
            s = get_ei(ei, is64, i);
            d = get_ei(ei, is64, (long)E + i);
        } else {
            s = d = i - E;
        }
        int li = i - beg;
        stash[li] = (s << BUCKET_SHIFT) | (d & 511);
        stashB[li] = (unsigned char)(d >> BUCKET_SHIFT);
        atomicAdd(&cnt[d >> BUCKET_SHIFT], 1);
    }
    __syncthreads();
    for (int b = tid; b < nbuk; b += 256) {
        int c = cnt[b];
        base[b] = c ? atomicAdd(&cur[b], c) : 0;
        cnt[b] = 0;                          // reuse as local cursor
    }
    __syncthreads();
    int cc = end - beg;
    for (int li = tid; li < cc; li += 256) {
        int b = stashB[li];
        int p = base[b] + atomicAdd(&cnt[b], 1);
        sorted[p] = stash[li];
    }
}

// ---------------------------------------------------------------------------
// D4: per-bucket finalize -> ptr + csr_src (unchanged logic, BB-based bounds).
// ---------------------------------------------------------------------------
__global__ __launch_bounds__(256) void p4_finalize(const int* __restrict__ BB,
                                                   const int* __restrict__ sorted,
                                                   int* __restrict__ ptr,
                                                   int* __restrict__ csr_src,
                                                   int n, int T) {
    int b = blockIdx.x;
    int tid = threadIdx.x;
    int node0 = b << BUCKET_SHIFT;
    int nn = n - node0; if (nn > 512) nn = 512;
    int beg = BB[b];
    int end = BB[b + 1];

    __shared__ int cnt[512];
    __shared__ int pair[256];
    __shared__ int exc[512];
    cnt[tid] = 0; cnt[tid + 256] = 0;
    __syncthreads();
    for (int j = beg + tid; j < end; j += 256) {
        int v = sorted[j];
        atomicAdd(&cnt[v & 511], 1);
    }
    __syncthreads();
    int psum = cnt[2 * tid] + cnt[2 * tid + 1];
    pair[tid] = psum;
    __syncthreads();
    for (int off = 1; off < 256; off <<= 1) {
        int u = (tid >= off) ? pair[tid - off] : 0;
        __syncthreads();
        pair[tid] += u;
        __syncthreads();
    }
    int pexc = pair[tid] - psum;
    exc[2 * tid] = pexc;
    exc[2 * tid + 1] = pexc + cnt[2 * tid];
    __syncthreads();
    for (int i = tid; i < nn; i += 256) ptr[node0 + i] = beg + exc[i];
    if (node0 + nn == n && tid == 0) ptr[n] = T;
    cnt[tid] = exc[tid]; cnt[tid + 256] = exc[tid + 256];
    __syncthreads();
    for (int j = beg + tid; j < end; j += 256) {
        int v = sorted[j];
        int p = beg + atomicAdd(&cnt[v & 511], 1);
        csr_src[p] = ((unsigned)v) >> BUCKET_SHIFT;
    }
}

// ---------------------------------------------------------------------------
// proj2 standalone (bf16 input from agg1).
// ---------------------------------------------------------------------------
__global__ __launch_bounds__(256) void proj2_kernel(const unsigned short* __restrict__ xin,
                                                    const unsigned short* __restrict__ wp2,
                                                    const float* __restrict__ as2,
                                                    const float* __restrict__ ad2,
                                                    unsigned short* __restrict__ h2,
                                                    float* __restrict__ asrc,
                                                    float* __restrict__ adst, int n) {
    proj_body<2, true>(xin, wp2, as2, ad2, h2, asrc, adst, n, blockIdx.x);
}

// ---------------------------------------------------------------------------
// Fused edge softmax + aggregation. Slot/f decomposition; 32 edges/iter with
// EIGHT independent h2 gathers in flight (4-deep measured 45.8, 2-deep 48.6
// -- MLP is the binding resource; same wasted-slot count at avg degree 17).
// ---------------------------------------------------------------------------
template <bool FMEAN>
__global__ __launch_bounds__(256) void agg_kernel(const int* __restrict__ ptr,
                                                  const int* __restrict__ srcs,
                                                  const unsigned short* __restrict__ h2,
                                                  const float* __restrict__ asrc,
                                                  const float* __restrict__ adst,
                                                  const float* __restrict__ bias,
                                                  unsigned short* __restrict__ outbf,
                                                  float* __restrict__ partials,
                                                  int n, int do_relu) {
    __shared__ int2  sm[4][64];
    __shared__ float red[256];
    int tid = threadIdx.x;
    int lane = tid & 63, wid = tid >> 6;
    int slot = lane >> 4, f = lane & 15;
    const char* h2b = (const char*)h2;
    unsigned fo = (unsigned)f << 3;
    float4 bv = *(const float4*)(bias + 4 * f);
    float ms0 = 0.f, ms1 = 0.f, ms2 = 0.f, ms3 = 0.f;

    int gwave = (blockIdx.x * blockDim.x + tid) >> 6;
    int nwaves = (gridDim.x * blockDim.x) >> 6;
    for (int node = gwave; node < n; node += nwaves) {
        int beg = ptr[node], end = ptr[node + 1];
        float ad = adst[node];
        float a0 = 0.f, a1 = 0.f, a2 = 0.f, a3 = 0.f, wsum = 0.f;
        for (int b = beg; b < end; b += 64) {
            int blen = end - b; if (blen > 64) blen = 64;
            int sv = 0; float wv = 0.f;
            if (lane < blen) {
                sv = srcs[b + lane];
                float e = asrc[sv] + ad;
                e = (e > 0.f) ? e : NEG_SLOPE * e;
                wv = __expf(e);
            }
            wsum += wv;
            sm[wid][lane] = make_int2(sv, __float_as_int(wv));
            int ni = (blen + 31) >> 5;           // 32 edges per iteration
            for (int j = 0; j < ni; ++j) {
                int2 swv[8];
#pragma unroll
                for (int u = 0; u < 8; ++u)
                    swv[u] = sm[wid][32 * j + 4 * u + slot];   // zero-padded
                uint2 g[8]; float w[8];
#pragma unroll
                for (int u = 0; u < 8; ++u) {
                    w[u] = __int_as_float(swv[u].y);
                    g[u] = *(const uint2*)(h2b + (((unsigned)swv[u].x << 7) + fo));
                }
#pragma unroll
                for (int u = 0; u < 8; ++u) {
                    a0 = fmaf(w[u], bflo(g[u].x), a0);
                    a1 = fmaf(w[u], bfhi(g[u].x), a1);
                    a2 = fmaf(w[u], bflo(g[u].y), a2);
                    a3 = fmaf(w[u], bfhi(g[u].y), a3);
                }
            }
        }
        a0 += __shfl_xor(a0, 16); a0 += __shfl_xor(a0, 32);
        a1 += __shfl_xor(a1, 16); a1 += __shfl_xor(a1, 32);
        a2 += __shfl_xor(a2, 16); a2 += __shfl_xor(a2, 32);
        a3 += __shfl_xor(a3, 16); a3 += __shfl_xor(a3, 32);
#pragma unroll
        for (int off = 32; off; off >>= 1) wsum += __shfl_xor(wsum, off);
        float inv = 1.f / (wsum + 1e-16f);
        float o0 = a0 * inv + bv.x;
        float o1 = a1 * inv + bv.y;
        float o2 = a2 * inv + bv.z;
        float o3 = a3 * inv + bv.w;
        if (!FMEAN) {
            if (do_relu) {
                o0 = fmaxf(o0, 0.f); o1 = fmaxf(o1, 0.f);
                o2 = fmaxf(o2, 0.f); o3 = fmaxf(o3, 0.f);
            }
            if (slot == 0) {
                u16x4 ov;
                ov[0] = f2bf(o0); ov[1] = f2bf(o1);
                ov[2] = f2bf(o2); ov[3] = f2bf(o3);
                *(u16x4*)(outbf + (size_t)node * 64 + 4 * f) = ov;
            }
        } else {
            if (slot == 0) { ms0 += o0; ms1 += o1; ms2 += o2; ms3 += o3; }
        }
    }
    if (FMEAN) {
        if (slot == 0)
            *(float4*)(red + wid * 64 + 4 * f) = make_float4(ms0, ms1, ms2, ms3);
        __syncthreads();
        if (tid < 64) {
            float t = red[tid] + red[64 + tid] + red[128 + tid] + red[192 + tid];
            partials[(size_t)blockIdx.x * 64 + tid] = t;
        }
    }
}

// ---------------------------------------------------------------------------
// Final mean: ONE block, non-atomic (no memset dispatch needed).
// partials is 2048 x 64 (512 KB, L2-resident).
// ---------------------------------------------------------------------------
__global__ __launch_bounds__(1024) void reduce_mean(const float* __restrict__ partials,
                                                    float* __restrict__ out,
                                                    int nb, float inv_n) {
    __shared__ float red[1024];
    int f = threadIdx.x & 63;
    int w = threadIdx.x >> 6;    // 16 row-groups
    float s = 0.f;
    for (int r = w; r < nb; r += 16) s += partials[(size_t)r * 64 + f];
    red[threadIdx.x] = s;
    __syncthreads();
    for (int step = 8; step >= 1; step >>= 1) {
        if (w < step) red[w * 64 + f] += red[(w + step) * 64 + f];
        __syncthreads();
    }
    if (w == 0) out[f] = red[f] * inv_n;
}

extern "C" void kernel_launch(void* const* d_in, const int* in_sizes, int n_in,
                              void* d_out, int out_size, void* d_ws, size_t ws_size,
                              hipStream_t stream) {
    const float* x   = (const float*)d_in[0];
    const int*   ei  = (const int*)d_in[1];
    // d_in[2] = edge_attr (unused by reference, edge_dim=None)
    const float* W1  = (const float*)d_in[3];
    const float* as1 = (const float*)d_in[4];
    const float* ad1 = (const float*)d_in[5];
    const float* b1  = (const float*)d_in[6];
    const float* W2  = (const float*)d_in[7];
    const float* as2 = (const float*)d_in[8];
    const float* ad2 = (const float*)d_in[9];
    const float* b2  = (const float*)d_in[10];
    float* out = (float*)d_out;

    const int N = in_sizes[0] / 128;  // 100000
    const int E = in_sizes[1] / 2;    // 1600000
    const int T = E + N;              // edges incl. self-loops

    const int NBUK  = (N + 511) >> BUCKET_SHIFT;      // 196
    const int NBLK  = (T + CHUNK - 1) / CHUNK;        // 416
    const int PGRID = (N + 63) / 64;                  // 1563
    const int AGRID = 2048;                           // grid-stride agg

    // Workspace carve-up (256B-aligned)
    size_t off = 0;
    char* base = (char*)d_ws;
    auto alloc = [&](size_t bytes) -> void* {
        void* p = base + off;
        off += (bytes + 255) & ~(size_t)255;
        return p;
    };
    int*   ptr     = (int*)alloc(((size_t)N + 1) * 4);
    int*   BT      = (int*)alloc(256 * 4);
    int*   BB      = (int*)alloc(257 * 4);
    int*   cur     = (int*)alloc(256 * 4);
    int*   csr_src = (int*)alloc((size_t)T * 4);
    float* asrc    = (float*)alloc((size_t)N * 4);
    float* adst    = (float*)alloc((size_t)N * 4);
    unsigned short* h2 = (unsigned short*)alloc((size_t)N * 64 * 2);
    // bufB: bf16 h1 (N*64*2) + overlays (sorted T*4, partials AGRID*64*4)
    unsigned short* bufB = (unsigned short*)alloc((size_t)N * 64 * 4);
    unsigned short* wp1 = (unsigned short*)alloc(16 * 64 * 8 * 2);  // 16 KB
    unsigned short* wp2 = (unsigned short*)alloc(8 * 64 * 8 * 2);   //  8 KB
    int*   sorted  = (int*)bufB;      // overlay: dead before agg1 writes bufB
    float* partials = (float*)bufB;   // overlay: bufB dead after proj2 reads it
    (void)ws_size;

    // D0: pack W + zero bucket totals
    prep_kernel<<<7, 256, 0, stream>>>(W1, W2, wp1, wp2, BT, NBUK);
    // D1: proj1 || p1 histogram (independent)
    fused1<<<PGRID + NBLK, 256, 0, stream>>>(x, wp1, as1, ad1, h2, asrc, adst, N,
                                             ei, BT, E, PGRID);
    // D2: tiny bucket scan -> BB, cur
    scan_bt<<<1, 256, 0, stream>>>(BT, BB, cur, NBUK);
    // D3: atomic-reservation scatter
    p3_scatter<<<NBLK, 256, 0, stream>>>(ei, cur, sorted, E, N);
    // D4: per-bucket finalize -> ptr, csr_src
    p4_finalize<<<NBUK, 256, 0, stream>>>(BB, sorted, ptr, csr_src, N, T);
    // D5: layer-1 aggregate (+ReLU, bf16 out)
    agg_kernel<false><<<AGRID, 256, 0, stream>>>(ptr, csr_src, h2, asrc, adst,
                                                 b1, bufB, nullptr, N, 1);
    // D6: layer-2 projection (bf16 in)
    proj2_kernel<<<PGRID, 256, 0, stream>>>(bufB, wp2, as2, ad2, h2, asrc, adst, N);
    // D7: layer-2 aggregate -> partials
    agg_kernel<true><<<AGRID, 256, 0, stream>>>(ptr, csr_src, h2, asrc, adst,
                                                b2, nullptr, partials, N, 0);
    // D8: single-block mean (non-atomic, overwrites out)
    reduce_mean<<<1, 1024, 0, stream>>>(partials, out, AGRID, 1.f / (float)N);
}

// Round 8
// 340.751 us; speedup vs baseline: 1.0618x; 1.0618x over previous
//
#include <hip/hip_runtime.h>
#include <hip/hip_bf16.h>
#include <cstdint>

#define NEG_SLOPE 0.2f
#define BUCKET_SHIFT 9    // 512 nodes per bucket
#define CHUNK 4096        // edges per bucketing block

typedef __attribute__((ext_vector_type(4))) int            i32x4;
typedef __attribute__((ext_vector_type(4))) float          f32x4;
typedef __attribute__((ext_vector_type(8))) unsigned short u16x8;
typedef __attribute__((ext_vector_type(4))) unsigned short u16x4;

__device__ inline unsigned short f2bf(float f) {  // round-to-nearest-even
    unsigned xi = __float_as_uint(f);
    unsigned r = xi + 0x7fffu + ((xi >> 16) & 1u);
    return (unsigned short)(r >> 16);
}
__device__ inline float bflo(unsigned g) { return __uint_as_float(g << 16); }
__device__ inline float bfhi(unsigned g) { return __uint_as_float(g & 0xffff0000u); }

__device__ inline int get_ei(const int* ei, int is64, long idx) {
    return is64 ? ei[2 * idx] : ei[(int)idx];
}

// In-block int64 detection: OR of odd words of the first 2048 src entries.
__device__ inline int detect_is64(const int* __restrict__ ei, int tid) {
    __shared__ int dred[4];
    int v = 0;
    for (int i = tid; i < 2048; i += 256) v |= ei[2 * i + 1];
#pragma unroll
    for (int off = 32; off; off >>= 1) v |= __shfl_xor(v, off);
    if ((tid & 63) == 0) dred[tid >> 6] = v;
    __syncthreads();
    int r = dred[0] | dred[1] | dred[2] | dred[3];
    __syncthreads();
    return (r == 0) ? 1 : 0;
}

// ---------------------------------------------------------------------------
// p1 body: per-chunk LDS histogram -> global atomicAdd into bucket totals BT.
// ---------------------------------------------------------------------------
__device__ void p1_body(const int* __restrict__ ei, int* __restrict__ BT,
                        int E, int n, int bid) {
    __shared__ int cnt[256];
    int tid = threadIdx.x;
    int is64 = detect_is64(ei, tid);
    int nbuk = (n + 511) >> BUCKET_SHIFT;
    for (int b = tid; b < nbuk; b += 256) cnt[b] = 0;
    __syncthreads();
    int total = E + n;
    int beg = bid * CHUNK;
    int end = beg + CHUNK; if (end > total) end = total;
    for (int i = beg + tid; i < end; i += 256) {
        int d = (i < E) ? get_ei(ei, is64, (long)E + i) : (i - E);
        atomicAdd(&cnt[d >> BUCKET_SHIFT], 1);
    }
    __syncthreads();
    for (int b = tid; b < nbuk; b += 256)
        if (cnt[b]) atomicAdd(&BT[b], cnt[b]);
}

// ---------------------------------------------------------------------------
// MFMA projection body (shared by fused D1 and standalone proj2).
// ---------------------------------------------------------------------------
#define MFMA_BF16(acc, a, b) \
    asm("s_nop 1\n\tv_mfma_f32_16x16x32_bf16 %0, %1, %2, %0" \
        : "+v"(acc) : "v"(a), "v"(b))

template <int KT, bool XBF>   // K = 32*KT
__device__ void proj_body(const void* __restrict__ xin,
                          const unsigned short* __restrict__ Wp,
                          const float* __restrict__ att_s,
                          const float* __restrict__ att_d,
                          unsigned short* __restrict__ h2,
                          float* __restrict__ asrc,
                          float* __restrict__ adst, int n, int bid) {
    constexpr int K = 32 * KT;
    __shared__ alignas(16) unsigned short lb[4][16 * 72];
    int tid = threadIdx.x;
    int wid = tid >> 6, l = tid & 63;
    int lm = l & 15, lg = l >> 4;

    int node0 = bid * 64 + wid * 16;
    if (node0 >= n) return;   // wave-uniform; no block barriers used

    float as_c[4], ad_c[4];
#pragma unroll
    for (int ct = 0; ct < 4; ++ct) {
        as_c[ct] = att_s[16 * ct + lm];
        ad_c[ct] = att_d[16 * ct + lm];
    }

    f32x4 acc[4] = {};
    int arow = node0 + lm;
    bool rowok = arow < n;

#pragma unroll
    for (int kt = 0; kt < KT; ++kt) {
        i32x4 af = {0, 0, 0, 0};
        if (XBF) {
            const unsigned short* xb = (const unsigned short*)xin
                                       + (size_t)arow * K + 32 * kt + 8 * lg;
            if (rowok) af = *(const i32x4*)xb;
        } else {
            const float* xp = (const float*)xin + (size_t)arow * K + 8 * lg + 32 * kt;
            float4 v0 = make_float4(0.f, 0.f, 0.f, 0.f);
            float4 v1 = v0;
            if (rowok) {
                v0 = *(const float4*)(xp);
                v1 = *(const float4*)(xp + 4);
            }
            af[0] = (int)((unsigned)f2bf(v0.x) | ((unsigned)f2bf(v0.y) << 16));
            af[1] = (int)((unsigned)f2bf(v0.z) | ((unsigned)f2bf(v0.w) << 16));
            af[2] = (int)((unsigned)f2bf(v1.x) | ((unsigned)f2bf(v1.y) << 16));
            af[3] = (int)((unsigned)f2bf(v1.z) | ((unsigned)f2bf(v1.w) << 16));
        }
#pragma unroll
        for (int ct = 0; ct < 4; ++ct) {
            i32x4 bf = *(const i32x4*)(Wp + (((kt * 4 + ct) * 64) + l) * 8);
            MFMA_BF16(acc[ct], af, bf);
        }
    }
    asm volatile("s_nop 7\n\ts_nop 7"
                 : "+v"(acc[0]), "+v"(acc[1]), "+v"(acc[2]), "+v"(acc[3]));

    float ps[4], pd[4];
#pragma unroll
    for (int r = 0; r < 4; ++r) {
        float s = 0.f, d = 0.f;
#pragma unroll
        for (int ct = 0; ct < 4; ++ct) {
            s = fmaf(acc[ct][r], as_c[ct], s);
            d = fmaf(acc[ct][r], ad_c[ct], d);
        }
        ps[r] = s; pd[r] = d;
    }
#pragma unroll
    for (int off = 1; off < 16; off <<= 1) {
#pragma unroll
        for (int r = 0; r < 4; ++r) {
            ps[r] += __shfl_xor(ps[r], off);
            pd[r] += __shfl_xor(pd[r], off);
        }
    }
    if (lm == 0) {
#pragma unroll
        for (int r = 0; r < 4; ++r) {
            int node = node0 + 4 * lg + r;
            if (node < n) { asrc[node] = ps[r]; adst[node] = pd[r]; }
        }
    }

    unsigned short* wb = lb[wid];
#pragma unroll
    for (int ct = 0; ct < 4; ++ct)
#pragma unroll
        for (int r = 0; r < 4; ++r)
            wb[(4 * lg + r) * 72 + 16 * ct + lm] = f2bf(acc[ct][r]);
    asm volatile("s_waitcnt lgkmcnt(0)" ::: "memory");
    int ch = l & 7;
#pragma unroll
    for (int p = 0; p < 2; ++p) {
        int rr = (l >> 3) + 8 * p;
        u16x8 ov = *(const u16x8*)(wb + rr * 72 + 8 * ch);
        int onode = node0 + rr;
        if (onode < n)
            *(u16x8*)(h2 + (size_t)onode * 64 + 8 * ch) = ov;
    }
}

// ---------------------------------------------------------------------------
// D0: pack W fragments (blocks 0..5) + zero bucket totals (block 6).
// ---------------------------------------------------------------------------
__global__ __launch_bounds__(256) void prep_kernel(const float* __restrict__ W1,
                                                   const float* __restrict__ W2,
                                                   unsigned short* __restrict__ wp1,
                                                   unsigned short* __restrict__ wp2,
                                                   int* __restrict__ BT, int nbuk) {
    if (blockIdx.x == 6) {
        for (int b = threadIdx.x; b < nbuk; b += 256) BT[b] = 0;
        return;
    }
    int t = blockIdx.x * 256 + threadIdx.x;   // < 1536 = 24 frags * 64 lanes
    int f = t >> 6, l = t & 63;
    int lm = l & 15, lg = l >> 4;
    const float* W = (f < 16) ? W1 : W2;
    unsigned short* wp = (f < 16) ? wp1 : wp2;
    int idx = (f < 16) ? f : (f - 16);
    int kt = idx >> 2, ct = idx & 3;
    union { u16x8 v; unsigned short u[8]; } o;
#pragma unroll
    for (int e = 0; e < 8; ++e)
        o.u[e] = f2bf(W[(size_t)(32 * kt + 8 * lg + e) * 64 + 16 * ct + lm]);
    *(u16x8*)(wp + ((size_t)idx * 64 + l) * 8) = o.v;
}

// ---------------------------------------------------------------------------
// D1: fused proj1 (blocks [0,pgrid)) || p1 histogram (blocks [pgrid, ...)).
// ---------------------------------------------------------------------------
__global__ __launch_bounds__(256) void fused1(const float* __restrict__ x,
                                              const unsigned short* __restrict__ wp1,
                                              const float* __restrict__ as1,
                                              const float* __restrict__ ad1,
                                              unsigned short* __restrict__ h2,
                                              float* __restrict__ asrc,
                                              float* __restrict__ adst, int n,
                                              const int* __restrict__ ei,
                                              int* __restrict__ BT, int E, int pgrid) {
    if ((int)blockIdx.x < pgrid)
        proj_body<4, false>(x, wp1, as1, ad1, h2, asrc, adst, n, blockIdx.x);
    else
        p1_body(ei, BT, E, n, blockIdx.x - pgrid);
}

// ---------------------------------------------------------------------------
// D2: one block -- exclusive scan of bucket totals -> BB (+sentinel), cur=BB.
// ---------------------------------------------------------------------------
__global__ __launch_bounds__(256) void scan_bt(const int* __restrict__ BT,
                                               int* __restrict__ BB,
                                               int* __restrict__ cur, int nbuk) {
    __shared__ int s[256];
    int t = threadIdx.x;
    int v = (t < nbuk) ? BT[t] : 0;
    s[t] = v;
    __syncthreads();
    for (int off = 1; off < 256; off <<= 1) {
        int u = (t >= off) ? s[t - off] : 0;
        __syncthreads();
        s[t] += u;
        __syncthreads();
    }
    int exc = s[t] - v;
    if (t < nbuk) { BB[t] = exc; cur[t] = exc; }
    if (t == 0) BB[nbuk] = s[255];    // total == T
}

// ---------------------------------------------------------------------------
// D3: scatter with atomic range reservation (order within bucket arbitrary).
// ---------------------------------------------------------------------------
__global__ __launch_bounds__(256) void p3_scatter(const int* __restrict__ ei,
                                                  int* __restrict__ cur,
                                                  int* __restrict__ sorted,
                                                  int E, int n) {
    __shared__ int stash[CHUNK];            // 16 KB
    __shared__ unsigned char stashB[CHUNK]; // 4 KB bucket ids (nbuk <= 256)
    __shared__ int cnt[256];
    __shared__ int base[256];
    int tid = threadIdx.x;
    int is64 = detect_is64(ei, tid);
    int nbuk = (n + 511) >> BUCKET_SHIFT;
    for (int b = tid; b < nbuk; b += 256) cnt[b] = 0;
    __syncthreads();
    int total = E + n;
    int beg = blockIdx.x * CHUNK;
    int end = beg + CHUNK; if (end > total) end = total;
    for (int i = beg + tid; i < end; i += 256) {
        int s, d;
        if (i < E) {
            s = get_ei(ei, is64, i);
            d = get_ei(ei, is64, (long)E + i);
        } else {
            s = d = i - E;
        }
        int li = i - beg;
        stash[li] = (s << BUCKET_SHIFT) | (d & 511);
        stashB[li] = (unsigned char)(d >> BUCKET_SHIFT);
        atomicAdd(&cnt[d >> BUCKET_SHIFT], 1);
    }
    __syncthreads();
    for (int b = tid; b < nbuk; b += 256) {
        int c = cnt[b];
        base[b] = c ? atomicAdd(&cur[b], c) : 0;
        cnt[b] = 0;                          // reuse as local cursor
    }
    __syncthreads();
    int cc = end - beg;
    for (int li = tid; li < cc; li += 256) {
        int b = stashB[li];
        int p = base[b] + atomicAdd(&cnt[b], 1);
        sorted[p] = stash[li];
    }
}

// ---------------------------------------------------------------------------
// D4: per-bucket finalize -> ptr + csr_src.
// ---------------------------------------------------------------------------
__global__ __launch_bounds__(256) void p4_finalize(const int* __restrict__ BB,
                                                   const int* __restrict__ sorted,
                                                   int* __restrict__ ptr,
                                                   int* __restrict__ csr_src,
                                                   int n, int T) {
    int b = blockIdx.x;
    int tid = threadIdx.x;
    int node0 = b << BUCKET_SHIFT;
    int nn = n - node0; if (nn > 512) nn = 512;
    int beg = BB[b];
    int end = BB[b + 1];

    __shared__ int cnt[512];
    __shared__ int pair[256];
    __shared__ int exc[512];
    cnt[tid] = 0; cnt[tid + 256] = 0;
    __syncthreads();
    for (int j = beg + tid; j < end; j += 256) {
        int v = sorted[j];
        atomicAdd(&cnt[v & 511], 1);
    }
    __syncthreads();
    int psum = cnt[2 * tid] + cnt[2 * tid + 1];
    pair[tid] = psum;
    __syncthreads();
    for (int off = 1; off < 256; off <<= 1) {
        int u = (tid >= off) ? pair[tid - off] : 0;
        __syncthreads();
        pair[tid] += u;
        __syncthreads();
    }
    int pexc = pair[tid] - psum;
    exc[2 * tid] = pexc;
    exc[2 * tid + 1] = pexc + cnt[2 * tid];
    __syncthreads();
    for (int i = tid; i < nn; i += 256) ptr[node0 + i] = beg + exc[i];
    if (node0 + nn == n && tid == 0) ptr[n] = T;
    cnt[tid] = exc[tid]; cnt[tid + 256] = exc[tid + 256];
    __syncthreads();
    for (int j = beg + tid; j < end; j += 256) {
        int v = sorted[j];
        int p = beg + atomicAdd(&cnt[v & 511], 1);
        csr_src[p] = ((unsigned)v) >> BUCKET_SHIFT;
    }
}

// ---------------------------------------------------------------------------
// proj2 standalone (bf16 input from agg1).
// ---------------------------------------------------------------------------
__global__ __launch_bounds__(256) void proj2_kernel(const unsigned short* __restrict__ xin,
                                                    const unsigned short* __restrict__ wp2,
                                                    const float* __restrict__ as2,
                                                    const float* __restrict__ ad2,
                                                    unsigned short* __restrict__ h2,
                                                    float* __restrict__ asrc,
                                                    float* __restrict__ adst, int n) {
    proj_body<2, true>(xin, wp2, as2, ad2, h2, asrc, adst, n, blockIdx.x);
}

// ---------------------------------------------------------------------------
// Fused edge softmax + aggregation. ONE NODE PER WAVE (25000 blocks -- the
// R6-proven schedule; R7's 2048-block grid-stride starved CUs: occ 70->42).
// Inner loop keeps depth-8: 32 edges/iter, EIGHT independent h2 gathers in
// flight (MLP is the measured binding resource: 2-deep 48.6, 4-deep 45.8).
// ---------------------------------------------------------------------------
template <bool FMEAN>
__global__ __launch_bounds__(256) void agg_kernel(const int* __restrict__ ptr,
                                                  const int* __restrict__ srcs,
                                                  const unsigned short* __restrict__ h2,
                                                  const float* __restrict__ asrc,
                                                  const float* __restrict__ adst,
                                                  const float* __restrict__ bias,
                                                  unsigned short* __restrict__ outbf,
                                                  float* __restrict__ partials,
                                                  int n, int do_relu) {
    __shared__ int2  sm[4][64];
    __shared__ float red[256];
    int tid = threadIdx.x;
    int lane = tid & 63, wid = tid >> 6;
    int slot = lane >> 4, f = lane & 15;
    const char* h2b = (const char*)h2;
    unsigned fo = (unsigned)f << 3;
    float4 bv = *(const float4*)(bias + 4 * f);
    float ms0 = 0.f, ms1 = 0.f, ms2 = 0.f, ms3 = 0.f;

    int gwave = (blockIdx.x * blockDim.x + tid) >> 6;
    int nwaves = (gridDim.x * blockDim.x) >> 6;
    for (int node = gwave; node < n; node += nwaves) {
        int beg = ptr[node], end = ptr[node + 1];
        float ad = adst[node];
        float a0 = 0.f, a1 = 0.f, a2 = 0.f, a3 = 0.f, wsum = 0.f;
        for (int b = beg; b < end; b += 64) {
            int blen = end - b; if (blen > 64) blen = 64;
            int sv = 0; float wv = 0.f;
            if (lane < blen) {
                sv = srcs[b + lane];
                float e = asrc[sv] + ad;
                e = (e > 0.f) ? e : NEG_SLOPE * e;
                wv = __expf(e);
            }
            wsum += wv;
            sm[wid][lane] = make_int2(sv, __float_as_int(wv));
            int ni = (blen + 31) >> 5;           // 32 edges per iteration
            for (int j = 0; j < ni; ++j) {
                int2 swv[8];
#pragma unroll
                for (int u = 0; u < 8; ++u)
                    swv[u] = sm[wid][32 * j + 4 * u + slot];   // zero-padded
                uint2 g[8]; float w[8];
#pragma unroll
                for (int u = 0; u < 8; ++u) {
                    w[u] = __int_as_float(swv[u].y);
                    g[u] = *(const uint2*)(h2b + (((unsigned)swv[u].x << 7) + fo));
                }
#pragma unroll
                for (int u = 0; u < 8; ++u) {
                    a0 = fmaf(w[u], bflo(g[u].x), a0);
                    a1 = fmaf(w[u], bfhi(g[u].x), a1);
                    a2 = fmaf(w[u], bflo(g[u].y), a2);
                    a3 = fmaf(w[u], bfhi(g[u].y), a3);
                }
            }
        }
        a0 += __shfl_xor(a0, 16); a0 += __shfl_xor(a0, 32);
        a1 += __shfl_xor(a1, 16); a1 += __shfl_xor(a1, 32);
        a2 += __shfl_xor(a2, 16); a2 += __shfl_xor(a2, 32);
        a3 += __shfl_xor(a3, 16); a3 += __shfl_xor(a3, 32);
#pragma unroll
        for (int off = 32; off; off >>= 1) wsum += __shfl_xor(wsum, off);
        float inv = 1.f / (wsum + 1e-16f);
        float o0 = a0 * inv + bv.x;
        float o1 = a1 * inv + bv.y;
        float o2 = a2 * inv + bv.z;
        float o3 = a3 * inv + bv.w;
        if (!FMEAN) {
            if (do_relu) {
                o0 = fmaxf(o0, 0.f); o1 = fmaxf(o1, 0.f);
                o2 = fmaxf(o2, 0.f); o3 = fmaxf(o3, 0.f);
            }
            if (slot == 0) {
                u16x4 ov;
                ov[0] = f2bf(o0); ov[1] = f2bf(o1);
                ov[2] = f2bf(o2); ov[3] = f2bf(o3);
                *(u16x4*)(outbf + (size_t)node * 64 + 4 * f) = ov;
            }
        } else {
            if (slot == 0) { ms0 += o0; ms1 += o1; ms2 += o2; ms3 += o3; }
        }
    }
    if (FMEAN) {
        if (slot == 0)
            *(float4*)(red + wid * 64 + 4 * f) = make_float4(ms0, ms1, ms2, ms3);
        __syncthreads();
        if (tid < 64) {
            float t = red[tid] + red[64 + tid] + red[128 + tid] + red[192 + tid];
            partials[(size_t)blockIdx.x * 64 + tid] = t;
        }
    }
}

// ---------------------------------------------------------------------------
// Two-stage non-atomic mean (no memset dispatch).
// Stage 1: 256 blocks, block b sums partials rows {b, b+256, ...}.
// Stage 2: 1 block over 256 rows.
// ---------------------------------------------------------------------------
__global__ __launch_bounds__(256) void reduce1(const float* __restrict__ partials,
                                               float* __restrict__ out256, int nb) {
    __shared__ float red[256];
    int f = threadIdx.x & 63;
    int w = threadIdx.x >> 6;
    float s = 0.f;
    for (int r = blockIdx.x + 256 * w; r < nb; r += 1024)
        s += partials[(size_t)r * 64 + f];
    red[threadIdx.x] = s;
    __syncthreads();
    if (w == 0) {
        float t = red[f] + red[64 + f] + red[128 + f] + red[192 + f];
        out256[(size_t)blockIdx.x * 64 + f] = t;
    }
}

__global__ __launch_bounds__(1024) void reduce2(const float* __restrict__ out256,
                                                float* __restrict__ out, float inv_n) {
    __shared__ float red[1024];
    int f = threadIdx.x & 63;
    int w = threadIdx.x >> 6;    // 16 row-groups over 256 rows
    float s = 0.f;
    for (int r = w; r < 256; r += 16) s += out256[(size_t)r * 64 + f];
    red[threadIdx.x] = s;
    __syncthreads();
    for (int step = 8; step >= 1; step >>= 1) {
        if (w < step) red[w * 64 + f] += red[(w + step) * 64 + f];
        __syncthreads();
    }
    if (w == 0) out[f] = red[f] * inv_n;
}

extern "C" void kernel_launch(void* const* d_in, const int* in_sizes, int n_in,
                              void* d_out, int out_size, void* d_ws, size_t ws_size,
                              hipStream_t stream) {
    const float* x   = (const float*)d_in[0];
    const int*   ei  = (const int*)d_in[1];
    // d_in[2] = edge_attr (unused by reference, edge_dim=None)
    const float* W1  = (const float*)d_in[3];
    const float* as1 = (const float*)d_in[4];
    const float* ad1 = (const float*)d_in[5];
    const float* b1  = (const float*)d_in[6];
    const float* W2  = (const float*)d_in[7];
    const float* as2 = (const float*)d_in[8];
    const float* ad2 = (const float*)d_in[9];
    const float* b2  = (const float*)d_in[10];
    float* out = (float*)d_out;

    const int N = in_sizes[0] / 128;  // 100000
    const int E = in_sizes[1] / 2;    // 1600000
    const int T = E + N;              // edges incl. self-loops

    const int NBUK  = (N + 511) >> BUCKET_SHIFT;      // 196
    const int NBLK  = (T + CHUNK - 1) / CHUNK;        // 416
    const int PGRID = (N + 63) / 64;                  // 1563
    const int AGRID = (N + 3) / 4;                    // 25000: one node per wave

    // Workspace carve-up (256B-aligned)
    size_t off = 0;
    char* base = (char*)d_ws;
    auto alloc = [&](size_t bytes) -> void* {
        void* p = base + off;
        off += (bytes + 255) & ~(size_t)255;
        return p;
    };
    int*   ptr     = (int*)alloc(((size_t)N + 1) * 4);
    int*   BT      = (int*)alloc(256 * 4);
    int*   BB      = (int*)alloc(257 * 4);
    int*   cur     = (int*)alloc(256 * 4);
    int*   csr_src = (int*)alloc((size_t)T * 4);
    float* asrc    = (float*)alloc((size_t)N * 4);
    float* adst    = (float*)alloc((size_t)N * 4);
    unsigned short* h2 = (unsigned short*)alloc((size_t)N * 64 * 2);
    // bufB: bf16 h1 (N*64*2) + overlays (sorted T*4, partials AGRID*64*4)
    unsigned short* bufB = (unsigned short*)alloc((size_t)N * 64 * 4);
    unsigned short* wp1 = (unsigned short*)alloc(16 * 64 * 8 * 2);  // 16 KB
    unsigned short* wp2 = (unsigned short*)alloc(8 * 64 * 8 * 2);   //  8 KB
    float* out256  = (float*)alloc(256 * 64 * 4);                   // 64 KB
    int*   sorted  = (int*)bufB;      // overlay: dead before agg1 writes bufB
    float* partials = (float*)bufB;   // overlay: bufB dead after proj2 reads it
    (void)ws_size;

    // D0: pack W + zero bucket totals
    prep_kernel<<<7, 256, 0, stream>>>(W1, W2, wp1, wp2, BT, NBUK);
    // D1: proj1 || p1 histogram (independent)
    fused1<<<PGRID + NBLK, 256, 0, stream>>>(x, wp1, as1, ad1, h2, asrc, adst, N,
                                             ei, BT, E, PGRID);
    // D2: tiny bucket scan -> BB, cur
    scan_bt<<<1, 256, 0, stream>>>(BT, BB, cur, NBUK);
    // D3: atomic-reservation scatter
    p3_scatter<<<NBLK, 256, 0, stream>>>(ei, cur, sorted, E, N);
    // D4: per-bucket finalize -> ptr, csr_src
    p4_finalize<<<NBUK, 256, 0, stream>>>(BB, sorted, ptr, csr_src, N, T);
    // D5: layer-1 aggregate (+ReLU, bf16 out)
    agg_kernel<false><<<AGRID, 256, 0, stream>>>(ptr, csr_src, h2, asrc, adst,
                                                 b1, bufB, nullptr, N, 1);
    // D6: layer-2 projection (bf16 in)
    proj2_kernel<<<PGRID, 256, 0, stream>>>(bufB, wp2, as2, ad2, h2, asrc, adst, N);
    // D7: layer-2 aggregate -> partials
    agg_kernel<true><<<AGRID, 256, 0, stream>>>(ptr, csr_src, h2, asrc, adst,
                                                b2, nullptr, partials, N, 0);
    // D8/D9: two-stage non-atomic mean
    reduce1<<<256, 256, 0, stream>>>(partials, out256, AGRID);
    reduce2<<<1, 1024, 0, stream>>>(out256, out, 1.f / (float)N);
}

// Round 9
// 315.246 us; speedup vs baseline: 1.1477x; 1.0809x over previous
//
#include <hip/hip_runtime.h>
#include <hip/hip_bf16.h>
#include <cstdint>

#define NEG_SLOPE 0.2f
#define BUCKET_SHIFT 9    // 512 nodes per bucket
#define CHUNK 4096        // edges per bucketing block

typedef __attribute__((ext_vector_type(4))) int            i32x4;
typedef __attribute__((ext_vector_type(4))) float          f32x4;
typedef __attribute__((ext_vector_type(8))) unsigned short u16x8;
typedef __attribute__((ext_vector_type(4))) unsigned short u16x4;

__device__ inline unsigned short f2bf(float f) {  // round-to-nearest-even
    unsigned xi = __float_as_uint(f);
    unsigned r = xi + 0x7fffu + ((xi >> 16) & 1u);
    return (unsigned short)(r >> 16);
}
__device__ inline float bflo(unsigned g) { return __uint_as_float(g << 16); }
__device__ inline float bfhi(unsigned g) { return __uint_as_float(g & 0xffff0000u); }

__device__ inline int get_ei(const int* ei, int is64, long idx) {
    return is64 ? ei[2 * idx] : ei[(int)idx];
}

// In-block int64 detection: OR of odd words of the first 2048 src entries.
__device__ inline int detect_is64(const int* __restrict__ ei, int tid) {
    __shared__ int dred[4];
    int v = 0;
    for (int i = tid; i < 2048; i += 256) v |= ei[2 * i + 1];
#pragma unroll
    for (int off = 32; off; off >>= 1) v |= __shfl_xor(v, off);
    if ((tid & 63) == 0) dred[tid >> 6] = v;
    __syncthreads();
    int r = dred[0] | dred[1] | dred[2] | dred[3];
    __syncthreads();
    return (r == 0) ? 1 : 0;
}

// ---------------------------------------------------------------------------
// p1 body: per-chunk LDS histogram -> global atomicAdd into bucket totals BT.
// ---------------------------------------------------------------------------
__device__ void p1_body(const int* __restrict__ ei, int* __restrict__ BT,
                        int E, int n, int bid) {
    __shared__ int cnt[256];
    int tid = threadIdx.x;
    int is64 = detect_is64(ei, tid);
    int nbuk = (n + 511) >> BUCKET_SHIFT;
    for (int b = tid; b < nbuk; b += 256) cnt[b] = 0;
    __syncthreads();
    int total = E + n;
    int beg = bid * CHUNK;
    int end = beg + CHUNK; if (end > total) end = total;
    for (int i = beg + tid; i < end; i += 256) {
        int d = (i < E) ? get_ei(ei, is64, (long)E + i) : (i - E);
        atomicAdd(&cnt[d >> BUCKET_SHIFT], 1);
    }
    __syncthreads();
    for (int b = tid; b < nbuk; b += 256)
        if (cnt[b]) atomicAdd(&BT[b], cnt[b]);
}

// ---------------------------------------------------------------------------
// MFMA projection body (shared by fused D1 and standalone proj2).
// ---------------------------------------------------------------------------
#define MFMA_BF16(acc, a, b) \
    asm("s_nop 1\n\tv_mfma_f32_16x16x32_bf16 %0, %1, %2, %0" \
        : "+v"(acc) : "v"(a), "v"(b))

template <int KT, bool XBF>   // K = 32*KT
__device__ void proj_body(const void* __restrict__ xin,
                          const unsigned short* __restrict__ Wp,
                          const float* __restrict__ att_s,
                          const float* __restrict__ att_d,
                          unsigned short* __restrict__ h2,
                          float* __restrict__ asrc,
                          float* __restrict__ adst, int n, int bid) {
    constexpr int K = 32 * KT;
    __shared__ alignas(16) unsigned short lb[4][16 * 72];
    int tid = threadIdx.x;
    int wid = tid >> 6, l = tid & 63;
    int lm = l & 15, lg = l >> 4;

    int node0 = bid * 64 + wid * 16;
    if (node0 >= n) return;   // wave-uniform; no block barriers used

    float as_c[4], ad_c[4];
#pragma unroll
    for (int ct = 0; ct < 4; ++ct) {
        as_c[ct] = att_s[16 * ct + lm];
        ad_c[ct] = att_d[16 * ct + lm];
    }

    f32x4 acc[4] = {};
    int arow = node0 + lm;
    bool rowok = arow < n;

#pragma unroll
    for (int kt = 0; kt < KT; ++kt) {
        i32x4 af = {0, 0, 0, 0};
        if (XBF) {
            const unsigned short* xb = (const unsigned short*)xin
                                       + (size_t)arow * K + 32 * kt + 8 * lg;
            if (rowok) af = *(const i32x4*)xb;
        } else {
            const float* xp = (const float*)xin + (size_t)arow * K + 8 * lg + 32 * kt;
            float4 v0 = make_float4(0.f, 0.f, 0.f, 0.f);
            float4 v1 = v0;
            if (rowok) {
                v0 = *(const float4*)(xp);
                v1 = *(const float4*)(xp + 4);
            }
            af[0] = (int)((unsigned)f2bf(v0.x) | ((unsigned)f2bf(v0.y) << 16));
            af[1] = (int)((unsigned)f2bf(v0.z) | ((unsigned)f2bf(v0.w) << 16));
            af[2] = (int)((unsigned)f2bf(v1.x) | ((unsigned)f2bf(v1.y) << 16));
            af[3] = (int)((unsigned)f2bf(v1.z) | ((unsigned)f2bf(v1.w) << 16));
        }
#pragma unroll
        for (int ct = 0; ct < 4; ++ct) {
            i32x4 bf = *(const i32x4*)(Wp + (((kt * 4 + ct) * 64) + l) * 8);
            MFMA_BF16(acc[ct], af, bf);
        }
    }
    asm volatile("s_nop 7\n\ts_nop 7"
                 : "+v"(acc[0]), "+v"(acc[1]), "+v"(acc[2]), "+v"(acc[3]));

    float ps[4], pd[4];
#pragma unroll
    for (int r = 0; r < 4; ++r) {
        float s = 0.f, d = 0.f;
#pragma unroll
        for (int ct = 0; ct < 4; ++ct) {
            s = fmaf(acc[ct][r], as_c[ct], s);
            d = fmaf(acc[ct][r], ad_c[ct], d);
        }
        ps[r] = s; pd[r] = d;
    }
#pragma unroll
    for (int off = 1; off < 16; off <<= 1) {
#pragma unroll
        for (int r = 0; r < 4; ++r) {
            ps[r] += __shfl_xor(ps[r], off);
            pd[r] += __shfl_xor(pd[r], off);
        }
    }
    if (lm == 0) {
#pragma unroll
        for (int r = 0; r < 4; ++r) {
            int node = node0 + 4 * lg + r;
            if (node < n) { asrc[node] = ps[r]; adst[node] = pd[r]; }
        }
    }

    unsigned short* wb = lb[wid];
#pragma unroll
    for (int ct = 0; ct < 4; ++ct)
#pragma unroll
        for (int r = 0; r < 4; ++r)
            wb[(4 * lg + r) * 72 + 16 * ct + lm] = f2bf(acc[ct][r]);
    asm volatile("s_waitcnt lgkmcnt(0)" ::: "memory");
    int ch = l & 7;
#pragma unroll
    for (int p = 0; p < 2; ++p) {
        int rr = (l >> 3) + 8 * p;
        u16x8 ov = *(const u16x8*)(wb + rr * 72 + 8 * ch);
        int onode = node0 + rr;
        if (onode < n)
            *(u16x8*)(h2 + (size_t)onode * 64 + 8 * ch) = ov;
    }
}

// ---------------------------------------------------------------------------
// D0: pack W fragments (blocks 0..5) + zero bucket totals (block 6).
// ---------------------------------------------------------------------------
__global__ __launch_bounds__(256) void prep_kernel(const float* __restrict__ W1,
                                                   const float* __restrict__ W2,
                                                   unsigned short* __restrict__ wp1,
                                                   unsigned short* __restrict__ wp2,
                                                   int* __restrict__ BT, int nbuk) {
    if (blockIdx.x == 6) {
        for (int b = threadIdx.x; b < nbuk; b += 256) BT[b] = 0;
        return;
    }
    int t = blockIdx.x * 256 + threadIdx.x;   // < 1536 = 24 frags * 64 lanes
    int f = t >> 6, l = t & 63;
    int lm = l & 15, lg = l >> 4;
    const float* W = (f < 16) ? W1 : W2;
    unsigned short* wp = (f < 16) ? wp1 : wp2;
    int idx = (f < 16) ? f : (f - 16);
    int kt = idx >> 2, ct = idx & 3;
    union { u16x8 v; unsigned short u[8]; } o;
#pragma unroll
    for (int e = 0; e < 8; ++e)
        o.u[e] = f2bf(W[(size_t)(32 * kt + 8 * lg + e) * 64 + 16 * ct + lm]);
    *(u16x8*)(wp + ((size_t)idx * 64 + l) * 8) = o.v;
}

// ---------------------------------------------------------------------------
// D1: fused proj1 (blocks [0,pgrid)) || p1 histogram (blocks [pgrid, ...)).
// ---------------------------------------------------------------------------
__global__ __launch_bounds__(256) void fused1(const float* __restrict__ x,
                                              const unsigned short* __restrict__ wp1,
                                              const float* __restrict__ as1,
                                              const float* __restrict__ ad1,
                                              unsigned short* __restrict__ h2,
                                              float* __restrict__ asrc,
                                              float* __restrict__ adst, int n,
                                              const int* __restrict__ ei,
                                              int* __restrict__ BT, int E, int pgrid) {
    if ((int)blockIdx.x < pgrid)
        proj_body<4, false>(x, wp1, as1, ad1, h2, asrc, adst, n, blockIdx.x);
    else
        p1_body(ei, BT, E, n, blockIdx.x - pgrid);
}

// ---------------------------------------------------------------------------
// D2: one block -- exclusive scan of bucket totals -> BB (+sentinel), cur=BB.
// ---------------------------------------------------------------------------
__global__ __launch_bounds__(256) void scan_bt(const int* __restrict__ BT,
                                               int* __restrict__ BB,
                                               int* __restrict__ cur, int nbuk) {
    __shared__ int s[256];
    int t = threadIdx.x;
    int v = (t < nbuk) ? BT[t] : 0;
    s[t] = v;
    __syncthreads();
    for (int off = 1; off < 256; off <<= 1) {
        int u = (t >= off) ? s[t - off] : 0;
        __syncthreads();
        s[t] += u;
        __syncthreads();
    }
    int exc = s[t] - v;
    if (t < nbuk) { BB[t] = exc; cur[t] = exc; }
    if (t == 0) BB[nbuk] = s[255];    // total == T
}

// ---------------------------------------------------------------------------
// D3: scatter with atomic range reservation (order within bucket arbitrary).
// ---------------------------------------------------------------------------
__global__ __launch_bounds__(256) void p3_scatter(const int* __restrict__ ei,
                                                  int* __restrict__ cur,
                                                  int* __restrict__ sorted,
                                                  int E, int n) {
    __shared__ int stash[CHUNK];            // 16 KB
    __shared__ unsigned char stashB[CHUNK]; // 4 KB bucket ids (nbuk <= 256)
    __shared__ int cnt[256];
    __shared__ int base[256];
    int tid = threadIdx.x;
    int is64 = detect_is64(ei, tid);
    int nbuk = (n + 511) >> BUCKET_SHIFT;
    for (int b = tid; b < nbuk; b += 256) cnt[b] = 0;
    __syncthreads();
    int total = E + n;
    int beg = blockIdx.x * CHUNK;
    int end = beg + CHUNK; if (end > total) end = total;
    for (int i = beg + tid; i < end; i += 256) {
        int s, d;
        if (i < E) {
            s = get_ei(ei, is64, i);
            d = get_ei(ei, is64, (long)E + i);
        } else {
            s = d = i - E;
        }
        int li = i - beg;
        stash[li] = (s << BUCKET_SHIFT) | (d & 511);
        stashB[li] = (unsigned char)(d >> BUCKET_SHIFT);
        atomicAdd(&cnt[d >> BUCKET_SHIFT], 1);
    }
    __syncthreads();
    for (int b = tid; b < nbuk; b += 256) {
        int c = cnt[b];
        base[b] = c ? atomicAdd(&cur[b], c) : 0;
        cnt[b] = 0;                          // reuse as local cursor
    }
    __syncthreads();
    int cc = end - beg;
    for (int li = tid; li < cc; li += 256) {
        int b = stashB[li];
        int p = base[b] + atomicAdd(&cnt[b], 1);
        sorted[p] = stash[li];
    }
}

// ---------------------------------------------------------------------------
// D4: per-bucket finalize -> ptr + csr_src.
// ---------------------------------------------------------------------------
__global__ __launch_bounds__(256) void p4_finalize(const int* __restrict__ BB,
                                                   const int* __restrict__ sorted,
                                                   int* __restrict__ ptr,
                                                   int* __restrict__ csr_src,
                                                   int n, int T) {
    int b = blockIdx.x;
    int tid = threadIdx.x;
    int node0 = b << BUCKET_SHIFT;
    int nn = n - node0; if (nn > 512) nn = 512;
    int beg = BB[b];
    int end = BB[b + 1];

    __shared__ int cnt[512];
    __shared__ int pair[256];
    __shared__ int exc[512];
    cnt[tid] = 0; cnt[tid + 256] = 0;
    __syncthreads();
    for (int j = beg + tid; j < end; j += 256) {
        int v = sorted[j];
        atomicAdd(&cnt[v & 511], 1);
    }
    __syncthreads();
    int psum = cnt[2 * tid] + cnt[2 * tid + 1];
    pair[tid] = psum;
    __syncthreads();
    for (int off = 1; off < 256; off <<= 1) {
        int u = (tid >= off) ? pair[tid - off] : 0;
        __syncthreads();
        pair[tid] += u;
        __syncthreads();
    }
    int pexc = pair[tid] - psum;
    exc[2 * tid] = pexc;
    exc[2 * tid + 1] = pexc + cnt[2 * tid];
    __syncthreads();
    for (int i = tid; i < nn; i += 256) ptr[node0 + i] = beg + exc[i];
    if (node0 + nn == n && tid == 0) ptr[n] = T;
    cnt[tid] = exc[tid]; cnt[tid + 256] = exc[tid + 256];
    __syncthreads();
    for (int j = beg + tid; j < end; j += 256) {
        int v = sorted[j];
        int p = beg + atomicAdd(&cnt[v & 511], 1);
        csr_src[p] = ((unsigned)v) >> BUCKET_SHIFT;
    }
}

// ---------------------------------------------------------------------------
// proj2 standalone (bf16 input from agg1).
// ---------------------------------------------------------------------------
__global__ __launch_bounds__(256) void proj2_kernel(const unsigned short* __restrict__ xin,
                                                    const unsigned short* __restrict__ wp2,
                                                    const float* __restrict__ as2,
                                                    const float* __restrict__ ad2,
                                                    unsigned short* __restrict__ h2,
                                                    float* __restrict__ asrc,
                                                    float* __restrict__ adst, int n) {
    proj_body<2, true>(xin, wp2, as2, ad2, h2, asrc, adst, n, blockIdx.x);
}

// ---------------------------------------------------------------------------
// Fused edge softmax + aggregation -- EXACT R6 configuration (measured 45.8us):
// one node per wave, depth-4 inner loop (16 edges/iter, FOUR independent h2
// gathers in flight). Depth-8 measured 59-62us (R7/R8): VGPR 28->44 and the
// single vmcnt(0) drain before 32 fmas break the compiler's load/compute
// interleave. Depth ladder: 2->48.6, 4->45.8, 8->62. Do not raise depth.
// ---------------------------------------------------------------------------
template <bool FMEAN>
__global__ __launch_bounds__(256) void agg_kernel(const int* __restrict__ ptr,
                                                  const int* __restrict__ srcs,
                                                  const unsigned short* __restrict__ h2,
                                                  const float* __restrict__ asrc,
                                                  const float* __restrict__ adst,
                                                  const float* __restrict__ bias,
                                                  unsigned short* __restrict__ outbf,
                                                  float* __restrict__ partials,
                                                  int n, int do_relu) {
    __shared__ int2  sm[4][64];
    __shared__ float red[256];
    int tid = threadIdx.x;
    int lane = tid & 63, wid = tid >> 6;
    int slot = lane >> 4, f = lane & 15;
    const char* h2b = (const char*)h2;
    unsigned fo = (unsigned)f << 3;
    float4 bv = *(const float4*)(bias + 4 * f);
    float ms0 = 0.f, ms1 = 0.f, ms2 = 0.f, ms3 = 0.f;

    int gwave = (blockIdx.x * blockDim.x + tid) >> 6;
    int nwaves = (gridDim.x * blockDim.x) >> 6;
    for (int node = gwave; node < n; node += nwaves) {
        int beg = ptr[node], end = ptr[node + 1];
        float ad = adst[node];
        float a0 = 0.f, a1 = 0.f, a2 = 0.f, a3 = 0.f, wsum = 0.f;
        for (int b = beg; b < end; b += 64) {
            int blen = end - b; if (blen > 64) blen = 64;
            int sv = 0; float wv = 0.f;
            if (lane < blen) {
                sv = srcs[b + lane];
                float e = asrc[sv] + ad;
                e = (e > 0.f) ? e : NEG_SLOPE * e;
                wv = __expf(e);
            }
            wsum += wv;
            sm[wid][lane] = make_int2(sv, __float_as_int(wv));
            int ni = (blen + 15) >> 4;           // 16 edges per iteration
            for (int j = 0; j < ni; ++j) {
                int2 swv[4];
#pragma unroll
                for (int u = 0; u < 4; ++u)
                    swv[u] = sm[wid][16 * j + 4 * u + slot];   // zero-padded
                uint2 g[4]; float w[4];
#pragma unroll
                for (int u = 0; u < 4; ++u) {
                    w[u] = __int_as_float(swv[u].y);
                    g[u] = *(const uint2*)(h2b + (((unsigned)swv[u].x << 7) + fo));
                }
#pragma unroll
                for (int u = 0; u < 4; ++u) {
                    a0 = fmaf(w[u], bflo(g[u].x), a0);
                    a1 = fmaf(w[u], bfhi(g[u].x), a1);
                    a2 = fmaf(w[u], bflo(g[u].y), a2);
                    a3 = fmaf(w[u], bfhi(g[u].y), a3);
                }
            }
        }
        a0 += __shfl_xor(a0, 16); a0 += __shfl_xor(a0, 32);
        a1 += __shfl_xor(a1, 16); a1 += __shfl_xor(a1, 32);
        a2 += __shfl_xor(a2, 16); a2 += __shfl_xor(a2, 32);
        a3 += __shfl_xor(a3, 16); a3 += __shfl_xor(a3, 32);
#pragma unroll
        for (int off = 32; off; off >>= 1) wsum += __shfl_xor(wsum, off);
        float inv = 1.f / (wsum + 1e-16f);
        float o0 = a0 * inv + bv.x;
        float o1 = a1 * inv + bv.y;
        float o2 = a2 * inv + bv.z;
        float o3 = a3 * inv + bv.w;
        if (!FMEAN) {
            if (do_relu) {
                o0 = fmaxf(o0, 0.f); o1 = fmaxf(o1, 0.f);
                o2 = fmaxf(o2, 0.f); o3 = fmaxf(o3, 0.f);
            }
            if (slot == 0) {
                u16x4 ov;
                ov[0] = f2bf(o0); ov[1] = f2bf(o1);
                ov[2] = f2bf(o2); ov[3] = f2bf(o3);
                *(u16x4*)(outbf + (size_t)node * 64 + 4 * f) = ov;
            }
        } else {
            if (slot == 0) { ms0 += o0; ms1 += o1; ms2 += o2; ms3 += o3; }
        }
    }
    if (FMEAN) {
        if (slot == 0)
            *(float4*)(red + wid * 64 + 4 * f) = make_float4(ms0, ms1, ms2, ms3);
        __syncthreads();
        if (tid < 64) {
            float t = red[tid] + red[64 + tid] + red[128 + tid] + red[192 + tid];
            partials[(size_t)blockIdx.x * 64 + tid] = t;
        }
    }
}

// ---------------------------------------------------------------------------
// Two-stage non-atomic mean (no memset dispatch).
// ---------------------------------------------------------------------------
__global__ __launch_bounds__(256) void reduce1(const float* __restrict__ partials,
                                               float* __restrict__ out256, int nb) {
    __shared__ float red[256];
    int f = threadIdx.x & 63;
    int w = threadIdx.x >> 6;
    float s = 0.f;
    for (int r = blockIdx.x + 256 * w; r < nb; r += 1024)
        s += partials[(size_t)r * 64 + f];
    red[threadIdx.x] = s;
    __syncthreads();
    if (w == 0) {
        float t = red[f] + red[64 + f] + red[128 + f] + red[192 + f];
        out256[(size_t)blockIdx.x * 64 + f] = t;
    }
}

__global__ __launch_bounds__(1024) void reduce2(const float* __restrict__ out256,
                                                float* __restrict__ out, float inv_n) {
    __shared__ float red[1024];
    int f = threadIdx.x & 63;
    int w = threadIdx.x >> 6;    // 16 row-groups over 256 rows
    float s = 0.f;
    for (int r = w; r < 256; r += 16) s += out256[(size_t)r * 64 + f];
    red[threadIdx.x] = s;
    __syncthreads();
    for (int step = 8; step >= 1; step >>= 1) {
        if (w < step) red[w * 64 + f] += red[(w + step) * 64 + f];
        __syncthreads();
    }
    if (w == 0) out[f] = red[f] * inv_n;
}

extern "C" void kernel_launch(void* const* d_in, const int* in_sizes, int n_in,
                              void* d_out, int out_size, void* d_ws, size_t ws_size,
                              hipStream_t stream) {
    const float* x   = (const float*)d_in[0];
    const int*   ei  = (const int*)d_in[1];
    // d_in[2] = edge_attr (unused by reference, edge_dim=None)
    const float* W1  = (const float*)d_in[3];
    const float* as1 = (const float*)d_in[4];
    const float* ad1 = (const float*)d_in[5];
    const float* b1  = (const float*)d_in[6];
    const float* W2  = (const float*)d_in[7];
    const float* as2 = (const float*)d_in[8];
    const float* ad2 = (const float*)d_in[9];
    const float* b2  = (const float*)d_in[10];
    float* out = (float*)d_out;

    const int N = in_sizes[0] / 128;  // 100000
    const int E = in_sizes[1] / 2;    // 1600000
    const int T = E + N;              // edges incl. self-loops

    const int NBUK  = (N + 511) >> BUCKET_SHIFT;      // 196
    const int NBLK  = (T + CHUNK - 1) / CHUNK;        // 416
    const int PGRID = (N + 63) / 64;                  // 1563
    const int AGRID = (N + 3) / 4;                    // 25000: one node per wave

    // Workspace carve-up (256B-aligned)
    size_t off = 0;
    char* base = (char*)d_ws;
    auto alloc = [&](size_t bytes) -> void* {
        void* p = base + off;
        off += (bytes + 255) & ~(size_t)255;
        return p;
    };
    int*   ptr     = (int*)alloc(((size_t)N + 1) * 4);
    int*   BT      = (int*)alloc(256 * 4);
    int*   BB      = (int*)alloc(257 * 4);
    int*   cur     = (int*)alloc(256 * 4);
    int*   csr_src = (int*)alloc((size_t)T * 4);
    float* asrc    = (float*)alloc((size_t)N * 4);
    float* adst    = (float*)alloc((size_t)N * 4);
    unsigned short* h2 = (unsigned short*)alloc((size_t)N * 64 * 2);
    // bufB: bf16 h1 (N*64*2) + overlays (sorted T*4, partials AGRID*64*4)
    unsigned short* bufB = (unsigned short*)alloc((size_t)N * 64 * 4);
    unsigned short* wp1 = (unsigned short*)alloc(16 * 64 * 8 * 2);  // 16 KB
    unsigned short* wp2 = (unsigned short*)alloc(8 * 64 * 8 * 2);   //  8 KB
    float* out256  = (float*)alloc(256 * 64 * 4);                   // 64 KB
    int*   sorted  = (int*)bufB;      // overlay: dead before agg1 writes bufB
    float* partials = (float*)bufB;   // overlay: bufB dead after proj2 reads it
    (void)ws_size;

    // D0: pack W + zero bucket totals
    prep_kernel<<<7, 256, 0, stream>>>(W1, W2, wp1, wp2, BT, NBUK);
    // D1: proj1 || p1 histogram (independent)
    fused1<<<PGRID + NBLK, 256, 0, stream>>>(x, wp1, as1, ad1, h2, asrc, adst, N,
                                             ei, BT, E, PGRID);
    // D2: tiny bucket scan -> BB, cur
    scan_bt<<<1, 256, 0, stream>>>(BT, BB, cur, NBUK);
    // D3: atomic-reservation scatter
    p3_scatter<<<NBLK, 256, 0, stream>>>(ei, cur, sorted, E, N);
    // D4: per-bucket finalize -> ptr, csr_src
    p4_finalize<<<NBUK, 256, 0, stream>>>(BB, sorted, ptr, csr_src, N, T);
    // D5: layer-1 aggregate (+ReLU, bf16 out)
    agg_kernel<false><<<AGRID, 256, 0, stream>>>(ptr, csr_src, h2, asrc, adst,
                                                 b1, bufB, nullptr, N, 1);
    // D6: layer-2 projection (bf16 in)
    proj2_kernel<<<PGRID, 256, 0, stream>>>(bufB, wp2, as2, ad2, h2, asrc, adst, N);
    // D7: layer-2 aggregate -> partials
    agg_kernel<true><<<AGRID, 256, 0, stream>>>(ptr, csr_src, h2, asrc, adst,
                                                b2, nullptr, partials, N, 0);
    // D8/D9: two-stage non-atomic mean
    reduce1<<<256, 256, 0, stream>>>(partials, out256, AGRID);
    reduce2<<<1, 1024, 0, stream>>>(out256, out, 1.f / (float)N);
}

// Round 10
// 293.784 us; speedup vs baseline: 1.2316x; 1.0731x over previous
//
#include <hip/hip_runtime.h>
#include <hip/hip_bf16.h>
#include <cstdint>

#define NEG_SLOPE 0.2f
#define BUCKET_SHIFT 9    // 512 nodes per bucket
#define CHUNK 4096        // edges per bucketing block

typedef __attribute__((ext_vector_type(4))) int            i32x4;
typedef __attribute__((ext_vector_type(4))) float          f32x4;
typedef __attribute__((ext_vector_type(8))) unsigned short u16x8;
typedef __attribute__((ext_vector_type(4))) unsigned short u16x4;

__device__ inline unsigned short f2bf(float f) {  // round-to-nearest-even
    unsigned xi = __float_as_uint(f);
    unsigned r = xi + 0x7fffu + ((xi >> 16) & 1u);
    return (unsigned short)(r >> 16);
}
__device__ inline float bflo(unsigned g) { return __uint_as_float(g << 16); }
__device__ inline float bfhi(unsigned g) { return __uint_as_float(g & 0xffff0000u); }

__device__ inline int get_ei(const int* ei, int is64, long idx) {
    return is64 ? ei[2 * idx] : ei[(int)idx];
}

// In-block int64 detection: OR of odd words of the first 2048 src entries.
__device__ inline int detect_is64(const int* __restrict__ ei, int tid) {
    __shared__ int dred[4];
    int v = 0;
    for (int i = tid; i < 2048; i += 256) v |= ei[2 * i + 1];
#pragma unroll
    for (int off = 32; off; off >>= 1) v |= __shfl_xor(v, off);
    if ((tid & 63) == 0) dred[tid >> 6] = v;
    __syncthreads();
    int r = dred[0] | dred[1] | dred[2] | dred[3];
    __syncthreads();
    return (r == 0) ? 1 : 0;
}

// ---------------------------------------------------------------------------
// p1 body: per-chunk LDS histogram -> global atomicAdd into bucket totals BT.
// ---------------------------------------------------------------------------
__device__ void p1_body(const int* __restrict__ ei, int* __restrict__ BT,
                        int E, int n, int bid) {
    __shared__ int cnt[256];
    int tid = threadIdx.x;
    int is64 = detect_is64(ei, tid);
    int nbuk = (n + 511) >> BUCKET_SHIFT;
    for (int b = tid; b < nbuk; b += 256) cnt[b] = 0;
    __syncthreads();
    int total = E + n;
    int beg = bid * CHUNK;
    int end = beg + CHUNK; if (end > total) end = total;
    for (int i = beg + tid; i < end; i += 256) {
        int d = (i < E) ? get_ei(ei, is64, (long)E + i) : (i - E);
        atomicAdd(&cnt[d >> BUCKET_SHIFT], 1);
    }
    __syncthreads();
    for (int b = tid; b < nbuk; b += 256)
        if (cnt[b]) atomicAdd(&BT[b], cnt[b]);
}

// ---------------------------------------------------------------------------
// MFMA projection body (shared by fused D1 and standalone proj2).
// ---------------------------------------------------------------------------
#define MFMA_BF16(acc, a, b) \
    asm("s_nop 1\n\tv_mfma_f32_16x16x32_bf16 %0, %1, %2, %0" \
        : "+v"(acc) : "v"(a), "v"(b))

template <int KT, bool XBF>   // K = 32*KT
__device__ void proj_body(const void* __restrict__ xin,
                          const unsigned short* __restrict__ Wp,
                          const float* __restrict__ att_s,
                          const float* __restrict__ att_d,
                          unsigned short* __restrict__ h2,
                          float* __restrict__ asrc,
                          float* __restrict__ adst, int n, int bid) {
    constexpr int K = 32 * KT;
    __shared__ alignas(16) unsigned short lb[4][16 * 72];
    int tid = threadIdx.x;
    int wid = tid >> 6, l = tid & 63;
    int lm = l & 15, lg = l >> 4;

    int node0 = bid * 64 + wid * 16;
    if (node0 >= n) return;   // wave-uniform; no block barriers used

    float as_c[4], ad_c[4];
#pragma unroll
    for (int ct = 0; ct < 4; ++ct) {
        as_c[ct] = att_s[16 * ct + lm];
        ad_c[ct] = att_d[16 * ct + lm];
    }

    f32x4 acc[4] = {};
    int arow = node0 + lm;
    bool rowok = arow < n;

#pragma unroll
    for (int kt = 0; kt < KT; ++kt) {
        i32x4 af = {0, 0, 0, 0};
        if (XBF) {
            const unsigned short* xb = (const unsigned short*)xin
                                       + (size_t)arow * K + 32 * kt + 8 * lg;
            if (rowok) af = *(const i32x4*)xb;
        } else {
            const float* xp = (const float*)xin + (size_t)arow * K + 8 * lg + 32 * kt;
            float4 v0 = make_float4(0.f, 0.f, 0.f, 0.f);
            float4 v1 = v0;
            if (rowok) {
                v0 = *(const float4*)(xp);
                v1 = *(const float4*)(xp + 4);
            }
            af[0] = (int)((unsigned)f2bf(v0.x) | ((unsigned)f2bf(v0.y) << 16));
            af[1] = (int)((unsigned)f2bf(v0.z) | ((unsigned)f2bf(v0.w) << 16));
            af[2] = (int)((unsigned)f2bf(v1.x) | ((unsigned)f2bf(v1.y) << 16));
            af[3] = (int)((unsigned)f2bf(v1.z) | ((unsigned)f2bf(v1.w) << 16));
        }
#pragma unroll
        for (int ct = 0; ct < 4; ++ct) {
            i32x4 bf = *(const i32x4*)(Wp + (((kt * 4 + ct) * 64) + l) * 8);
            MFMA_BF16(acc[ct], af, bf);
        }
    }
    asm volatile("s_nop 7\n\ts_nop 7"
                 : "+v"(acc[0]), "+v"(acc[1]), "+v"(acc[2]), "+v"(acc[3]));

    float ps[4], pd[4];
#pragma unroll
    for (int r = 0; r < 4; ++r) {
        float s = 0.f, d = 0.f;
#pragma unroll
        for (int ct = 0; ct < 4; ++ct) {
            s = fmaf(acc[ct][r], as_c[ct], s);
            d = fmaf(acc[ct][r], ad_c[ct], d);
        }
        ps[r] = s; pd[r] = d;
    }
#pragma unroll
    for (int off = 1; off < 16; off <<= 1) {
#pragma unroll
        for (int r = 0; r < 4; ++r) {
            ps[r] += __shfl_xor(ps[r], off);
            pd[r] += __shfl_xor(pd[r], off);
        }
    }
    if (lm == 0) {
#pragma unroll
        for (int r = 0; r < 4; ++r) {
            int node = node0 + 4 * lg + r;
            if (node < n) { asrc[node] = ps[r]; adst[node] = pd[r]; }
        }
    }

    unsigned short* wb = lb[wid];
#pragma unroll
    for (int ct = 0; ct < 4; ++ct)
#pragma unroll
        for (int r = 0; r < 4; ++r)
            wb[(4 * lg + r) * 72 + 16 * ct + lm] = f2bf(acc[ct][r]);
    asm volatile("s_waitcnt lgkmcnt(0)" ::: "memory");
    int ch = l & 7;
#pragma unroll
    for (int p = 0; p < 2; ++p) {
        int rr = (l >> 3) + 8 * p;
        u16x8 ov = *(const u16x8*)(wb + rr * 72 + 8 * ch);
        int onode = node0 + rr;
        if (onode < n)
            *(u16x8*)(h2 + (size_t)onode * 64 + 8 * ch) = ov;
    }
}

// ---------------------------------------------------------------------------
// D0: pack W fragments (blocks 0..5) + zero bucket totals (block 6).
// ---------------------------------------------------------------------------
__global__ __launch_bounds__(256) void prep_kernel(const float* __restrict__ W1,
                                                   const float* __restrict__ W2,
                                                   unsigned short* __restrict__ wp1,
                                                   unsigned short* __restrict__ wp2,
                                                   int* __restrict__ BT, int nbuk) {
    if (blockIdx.x == 6) {
        for (int b = threadIdx.x; b < nbuk; b += 256) BT[b] = 0;
        return;
    }
    int t = blockIdx.x * 256 + threadIdx.x;   // < 1536 = 24 frags * 64 lanes
    int f = t >> 6, l = t & 63;
    int lm = l & 15, lg = l >> 4;
    const float* W = (f < 16) ? W1 : W2;
    unsigned short* wp = (f < 16) ? wp1 : wp2;
    int idx = (f < 16) ? f : (f - 16);
    int kt = idx >> 2, ct = idx & 3;
    union { u16x8 v; unsigned short u[8]; } o;
#pragma unroll
    for (int e = 0; e < 8; ++e)
        o.u[e] = f2bf(W[(size_t)(32 * kt + 8 * lg + e) * 64 + 16 * ct + lm]);
    *(u16x8*)(wp + ((size_t)idx * 64 + l) * 8) = o.v;
}

// ---------------------------------------------------------------------------
// D1: fused proj1 (blocks [0,pgrid)) || p1 histogram (blocks [pgrid, ...)).
// ---------------------------------------------------------------------------
__global__ __launch_bounds__(256) void fused1(const float* __restrict__ x,
                                              const unsigned short* __restrict__ wp1,
                                              const float* __restrict__ as1,
                                              const float* __restrict__ ad1,
                                              unsigned short* __restrict__ h2,
                                              float* __restrict__ asrc,
                                              float* __restrict__ adst, int n,
                                              const int* __restrict__ ei,
                                              int* __restrict__ BT, int E, int pgrid) {
    if ((int)blockIdx.x < pgrid)
        proj_body<4, false>(x, wp1, as1, ad1, h2, asrc, adst, n, blockIdx.x);
    else
        p1_body(ei, BT, E, n, blockIdx.x - pgrid);
}

// ---------------------------------------------------------------------------
// D2: one block -- exclusive scan of bucket totals -> BB (+sentinel), cur=BB.
// ---------------------------------------------------------------------------
__global__ __launch_bounds__(256) void scan_bt(const int* __restrict__ BT,
                                               int* __restrict__ BB,
                                               int* __restrict__ cur, int nbuk) {
    __shared__ int s[256];
    int t = threadIdx.x;
    int v = (t < nbuk) ? BT[t] : 0;
    s[t] = v;
    __syncthreads();
    for (int off = 1; off < 256; off <<= 1) {
        int u = (t >= off) ? s[t - off] : 0;
        __syncthreads();
        s[t] += u;
        __syncthreads();
    }
    int exc = s[t] - v;
    if (t < nbuk) { BB[t] = exc; cur[t] = exc; }
    if (t == 0) BB[nbuk] = s[255];    // total == T
}

// ---------------------------------------------------------------------------
// D3: scatter with atomic range reservation (order within bucket arbitrary).
// ---------------------------------------------------------------------------
__global__ __launch_bounds__(256) void p3_scatter(const int* __restrict__ ei,
                                                  int* __restrict__ cur,
                                                  int* __restrict__ sorted,
                                                  int E, int n) {
    __shared__ int stash[CHUNK];            // 16 KB
    __shared__ unsigned char stashB[CHUNK]; // 4 KB bucket ids (nbuk <= 256)
    __shared__ int cnt[256];
    __shared__ int base[256];
    int tid = threadIdx.x;
    int is64 = detect_is64(ei, tid);
    int nbuk = (n + 511) >> BUCKET_SHIFT;
    for (int b = tid; b < nbuk; b += 256) cnt[b] = 0;
    __syncthreads();
    int total = E + n;
    int beg = blockIdx.x * CHUNK;
    int end = beg + CHUNK; if (end > total) end = total;
    for (int i = beg + tid; i < end; i += 256) {
        int s, d;
        if (i < E) {
            s = get_ei(ei, is64, i);
            d = get_ei(ei, is64, (long)E + i);
        } else {
            s = d = i - E;
        }
        int li = i - beg;
        stash[li] = (s << BUCKET_SHIFT) | (d & 511);
        stashB[li] = (unsigned char)(d >> BUCKET_SHIFT);
        atomicAdd(&cnt[d >> BUCKET_SHIFT], 1);
    }
    __syncthreads();
    for (int b = tid; b < nbuk; b += 256) {
        int c = cnt[b];
        base[b] = c ? atomicAdd(&cur[b], c) : 0;
        cnt[b] = 0;                          // reuse as local cursor
    }
    __syncthreads();
    int cc = end - beg;
    for (int li = tid; li < cc; li += 256) {
        int b = stashB[li];
        int p = base[b] + atomicAdd(&cnt[b], 1);
        sorted[p] = stash[li];
    }
}

// ---------------------------------------------------------------------------
// D4: per-bucket finalize -> ptr + csr_src.
// ---------------------------------------------------------------------------
__global__ __launch_bounds__(256) void p4_finalize(const int* __restrict__ BB,
                                                   const int* __restrict__ sorted,
                                                   int* __restrict__ ptr,
                                                   int* __restrict__ csr_src,
                                                   int n, int T) {
    int b = blockIdx.x;
    int tid = threadIdx.x;
    int node0 = b << BUCKET_SHIFT;
    int nn = n - node0; if (nn > 512) nn = 512;
    int beg = BB[b];
    int end = BB[b + 1];

    __shared__ int cnt[512];
    __shared__ int pair[256];
    __shared__ int exc[512];
    cnt[tid] = 0; cnt[tid + 256] = 0;
    __syncthreads();
    for (int j = beg + tid; j < end; j += 256) {
        int v = sorted[j];
        atomicAdd(&cnt[v & 511], 1);
    }
    __syncthreads();
    int psum = cnt[2 * tid] + cnt[2 * tid + 1];
    pair[tid] = psum;
    __syncthreads();
    for (int off = 1; off < 256; off <<= 1) {
        int u = (tid >= off) ? pair[tid - off] : 0;
        __syncthreads();
        pair[tid] += u;
        __syncthreads();
    }
    int pexc = pair[tid] - psum;
    exc[2 * tid] = pexc;
    exc[2 * tid + 1] = pexc + cnt[2 * tid];
    __syncthreads();
    for (int i = tid; i < nn; i += 256) ptr[node0 + i] = beg + exc[i];
    if (node0 + nn == n && tid == 0) ptr[n] = T;
    cnt[tid] = exc[tid]; cnt[tid + 256] = exc[tid + 256];
    __syncthreads();
    for (int j = beg + tid; j < end; j += 256) {
        int v = sorted[j];
        int p = beg + atomicAdd(&cnt[v & 511], 1);
        csr_src[p] = ((unsigned)v) >> BUCKET_SHIFT;
    }
}

// ---------------------------------------------------------------------------
// proj2 standalone (bf16 input from agg1).
// ---------------------------------------------------------------------------
__global__ __launch_bounds__(256) void proj2_kernel(const unsigned short* __restrict__ xin,
                                                    const unsigned short* __restrict__ wp2,
                                                    const float* __restrict__ as2,
                                                    const float* __restrict__ ad2,
                                                    unsigned short* __restrict__ h2,
                                                    float* __restrict__ asrc,
                                                    float* __restrict__ adst, int n) {
    proj_body<2, true>(xin, wp2, as2, ad2, h2, asrc, adst, n, blockIdx.x);
}

// ---------------------------------------------------------------------------
// Fused edge softmax + aggregation -- ONE NODE PER 16-LANE GROUP.
// f = lane&15 owns features 4f..4f+3 exclusively -> no cross-lane a-reduce
// (the old slot/f scheme duplicated features across 4 slots and paid 8
// shfl_xor per node). Edge granularity drops 16 -> 4: E[slots/node] goes
// 24.8 -> 18.8 at deg~Pois(16)+1 (-24% gather work). Depth-4 MLP kept: per
// iteration each lane issues 4 independent h2 row gathers (depth ladder:
// 2->48.6, 4->45.8, 8->62 -- do not raise depth).
// (src,w) broadcast via per-group LDS stash padded to 17 int2 (group stride
// 34 words -> groups land on distinct banks; fill writes 2-way = free m136).
// 6250 blocks x 16 groups = exactly N nodes, one per group (self-balancing
// short blocks -- R7's long grid-stride starved CUs, occ 70->42).
// ---------------------------------------------------------------------------
template <bool FMEAN>
__global__ __launch_bounds__(256) void agg_kernel(const int* __restrict__ ptr,
                                                  const int* __restrict__ srcs,
                                                  const unsigned short* __restrict__ h2,
                                                  const float* __restrict__ asrc,
                                                  const float* __restrict__ adst,
                                                  const float* __restrict__ bias,
                                                  unsigned short* __restrict__ outbf,
                                                  float* __restrict__ partials,
                                                  int n, int do_relu) {
    __shared__ int2  sm[4][4][17];     // [wave][group][16 + pad]
    __shared__ float4 red4[256];
    int tid = threadIdx.x;
    int lane = tid & 63, wid = tid >> 6;
    int grp = lane >> 4, f = lane & 15;
    const char* h2b = (const char*)h2;
    unsigned fo = (unsigned)f << 3;    // byte offset of uint2 (4 bf16) in row
    float4 bv = *(const float4*)(bias + 4 * f);
    float ms0 = 0.f, ms1 = 0.f, ms2 = 0.f, ms3 = 0.f;

    int gg = (blockIdx.x * blockDim.x + tid) >> 4;   // global group id
    int ng = (gridDim.x * blockDim.x) >> 4;
    for (int node = gg; node < n; node += ng) {
        int beg = ptr[node], end = ptr[node + 1];
        float ad = adst[node];
        float a0 = 0.f, a1 = 0.f, a2 = 0.f, a3 = 0.f, wsum = 0.f;
        for (int b = beg; b < end; b += 16) {
            int blen = end - b; if (blen > 16) blen = 16;
            int sv = 0; float wv = 0.f;
            if (f < blen) {
                sv = srcs[b + f];                // 64B coalesced per group
                float e = asrc[sv] + ad;         // L2-resident 4B gather
                e = (e > 0.f) ? e : NEG_SLOPE * e;
                wv = __expf(e);
            }
            wsum += wv;
            sm[wid][grp][f] = make_int2(sv, __float_as_int(wv));  // wave-sync
            int ni = (blen + 3) >> 2;            // 4 edges per iteration
            for (int j = 0; j < ni; ++j) {
                int2 swv[4];
#pragma unroll
                for (int u = 0; u < 4; ++u)
                    swv[u] = sm[wid][grp][4 * j + u];   // group broadcast
                uint2 g[4]; float w[4];
#pragma unroll
                for (int u = 0; u < 4; ++u) {
                    w[u] = __int_as_float(swv[u].y);
                    g[u] = *(const uint2*)(h2b + (((unsigned)swv[u].x << 7) + fo));
                }
#pragma unroll
                for (int u = 0; u < 4; ++u) {
                    a0 = fmaf(w[u], bflo(g[u].x), a0);
                    a1 = fmaf(w[u], bfhi(g[u].x), a1);
                    a2 = fmaf(w[u], bflo(g[u].y), a2);
                    a3 = fmaf(w[u], bfhi(g[u].y), a3);
                }
            }
        }
        // wsum reduce within the 16-lane group; features need no reduction.
        wsum += __shfl_xor(wsum, 1);
        wsum += __shfl_xor(wsum, 2);
        wsum += __shfl_xor(wsum, 4);
        wsum += __shfl_xor(wsum, 8);
        float inv = 1.f / (wsum + 1e-16f);
        float o0 = a0 * inv + bv.x;
        float o1 = a1 * inv + bv.y;
        float o2 = a2 * inv + bv.z;
        float o3 = a3 * inv + bv.w;
        if (!FMEAN) {
            if (do_relu) {
                o0 = fmaxf(o0, 0.f); o1 = fmaxf(o1, 0.f);
                o2 = fmaxf(o2, 0.f); o3 = fmaxf(o3, 0.f);
            }
            u16x4 ov;
            ov[0] = f2bf(o0); ov[1] = f2bf(o1);
            ov[2] = f2bf(o2); ov[3] = f2bf(o3);
            *(u16x4*)(outbf + (size_t)node * 64 + 4 * f) = ov;  // 128B/row
        } else {
            ms0 += o0; ms1 += o1; ms2 += o2; ms3 += o3;
        }
    }
    if (FMEAN) {
        red4[tid] = make_float4(ms0, ms1, ms2, ms3);   // tid = t'*16 + f
        __syncthreads();
        if (tid < 16) {
            float4 s = make_float4(0.f, 0.f, 0.f, 0.f);
#pragma unroll
            for (int r = 0; r < 16; ++r) {
                float4 v = red4[r * 16 + tid];
                s.x += v.x; s.y += v.y; s.z += v.z; s.w += v.w;
            }
            *(float4*)(partials + (size_t)blockIdx.x * 64 + 4 * tid) = s;
        }
    }
}

// ---------------------------------------------------------------------------
// Two-stage non-atomic mean (no memset dispatch).
// ---------------------------------------------------------------------------
__global__ __launch_bounds__(256) void reduce1(const float* __restrict__ partials,
                                               float* __restrict__ out256, int nb) {
    __shared__ float red[256];
    int f = threadIdx.x & 63;
    int w = threadIdx.x >> 6;
    float s = 0.f;
    for (int r = blockIdx.x + 256 * w; r < nb; r += 1024)
        s += partials[(size_t)r * 64 + f];
    red[threadIdx.x] = s;
    __syncthreads();
    if (w == 0) {
        float t = red[f] + red[64 + f] + red[128 + f] + red[192 + f];
        out256[(size_t)blockIdx.x * 64 + f] = t;
    }
}

__global__ __launch_bounds__(1024) void reduce2(const float* __restrict__ out256,
                                                float* __restrict__ out, float inv_n) {
    __shared__ float red[1024];
    int f = threadIdx.x & 63;
    int w = threadIdx.x >> 6;    // 16 row-groups over 256 rows
    float s = 0.f;
    for (int r = w; r < 256; r += 16) s += out256[(size_t)r * 64 + f];
    red[threadIdx.x] = s;
    __syncthreads();
    for (int step = 8; step >= 1; step >>= 1) {
        if (w < step) red[w * 64 + f] += red[(w + step) * 64 + f];
        __syncthreads();
    }
    if (w == 0) out[f] = red[f] * inv_n;
}

extern "C" void kernel_launch(void* const* d_in, const int* in_sizes, int n_in,
                              void* d_out, int out_size, void* d_ws, size_t ws_size,
                              hipStream_t stream) {
    const float* x   = (const float*)d_in[0];
    const int*   ei  = (const int*)d_in[1];
    // d_in[2] = edge_attr (unused by reference, edge_dim=None)
    const float* W1  = (const float*)d_in[3];
    const float* as1 = (const float*)d_in[4];
    const float* ad1 = (const float*)d_in[5];
    const float* b1  = (const float*)d_in[6];
    const float* W2  = (const float*)d_in[7];
    const float* as2 = (const float*)d_in[8];
    const float* ad2 = (const float*)d_in[9];
    const float* b2  = (const float*)d_in[10];
    float* out = (float*)d_out;

    const int N = in_sizes[0] / 128;  // 100000
    const int E = in_sizes[1] / 2;    // 1600000
    const int T = E + N;              // edges incl. self-loops

    const int NBUK  = (N + 511) >> BUCKET_SHIFT;      // 196
    const int NBLK  = (T + CHUNK - 1) / CHUNK;        // 416
    const int PGRID = (N + 63) / 64;                  // 1563
    const int AGRID = (N + 15) / 16;                  // 6250: one node per group

    // Workspace carve-up (256B-aligned)
    size_t off = 0;
    char* base = (char*)d_ws;
    auto alloc = [&](size_t bytes) -> void* {
        void* p = base + off;
        off += (bytes + 255) & ~(size_t)255;
        return p;
    };
    int*   ptr     = (int*)alloc(((size_t)N + 1) * 4);
    int*   BT      = (int*)alloc(256 * 4);
    int*   BB      = (int*)alloc(257 * 4);
    int*   cur     = (int*)alloc(256 * 4);
    int*   csr_src = (int*)alloc((size_t)T * 4);
    float* asrc    = (float*)alloc((size_t)N * 4);
    float* adst    = (float*)alloc((size_t)N * 4);
    unsigned short* h2 = (unsigned short*)alloc((size_t)N * 64 * 2);
    // bufB: bf16 h1 (N*64*2) + overlays (sorted T*4, partials AGRID*64*4)
    unsigned short* bufB = (unsigned short*)alloc((size_t)N * 64 * 4);
    unsigned short* wp1 = (unsigned short*)alloc(16 * 64 * 8 * 2);  // 16 KB
    unsigned short* wp2 = (unsigned short*)alloc(8 * 64 * 8 * 2);   //  8 KB
    float* out256  = (float*)alloc(256 * 64 * 4);                   // 64 KB
    int*   sorted  = (int*)bufB;      // overlay: dead before agg1 writes bufB
    float* partials = (float*)bufB;   // overlay: bufB dead after proj2 reads it
    (void)ws_size;

    // D0: pack W + zero bucket totals
    prep_kernel<<<7, 256, 0, stream>>>(W1, W2, wp1, wp2, BT, NBUK);
    // D1: proj1 || p1 histogram (independent)
    fused1<<<PGRID + NBLK, 256, 0, stream>>>(x, wp1, as1, ad1, h2, asrc, adst, N,
                                             ei, BT, E, PGRID);
    // D2: tiny bucket scan -> BB, cur
    scan_bt<<<1, 256, 0, stream>>>(BT, BB, cur, NBUK);
    // D3: atomic-reservation scatter
    p3_scatter<<<NBLK, 256, 0, stream>>>(ei, cur, sorted, E, N);
    // D4: per-bucket finalize -> ptr, csr_src
    p4_finalize<<<NBUK, 256, 0, stream>>>(BB, sorted, ptr, csr_src, N, T);
    // D5: layer-1 aggregate (+ReLU, bf16 out)
    agg_kernel<false><<<AGRID, 256, 0, stream>>>(ptr, csr_src, h2, asrc, adst,
                                                 b1, bufB, nullptr, N, 1);
    // D6: layer-2 projection (bf16 in)
    proj2_kernel<<<PGRID, 256, 0, stream>>>(bufB, wp2, as2, ad2, h2, asrc, adst, N);
    // D7: layer-2 aggregate -> partials
    agg_kernel<true><<<AGRID, 256, 0, stream>>>(ptr, csr_src, h2, asrc, adst,
                                                b2, nullptr, partials, N, 0);
    // D8/D9: two-stage non-atomic mean
    reduce1<<<256, 256, 0, stream>>>(partials, out256, AGRID);
    reduce2<<<1, 1024, 0, stream>>>(out256, out, 1.f / (float)N);
}